// Round 17
// baseline (553.146 us; speedup 1.0000x reference)
//
#include <hip/hip_runtime.h>

typedef unsigned short u16;
typedef __bf16 bf16_t;
typedef bf16_t bf16x8 __attribute__((ext_vector_type(8)));
typedef float f32x4 __attribute__((ext_vector_type(4)));
typedef float f32x16 __attribute__((ext_vector_type(16)));

#define LOG2E 1.4426950408889634f
#define QKVS 6144  // row stride of fused QKV activation buffer

__device__ __forceinline__ u16 f2bf(float f) {
  union { float f; unsigned u; } c; c.f = f;
  unsigned r = c.u + 0x7fffu + ((c.u >> 16) & 1u);
  return (u16)(r >> 16);
}
__device__ __forceinline__ float bf2f(u16 u) {
  union { unsigned u; float f; } c; c.u = ((unsigned)u) << 16;
  return c.f;
}

__device__ __forceinline__ void gload16(const void* g, void* l) {
  __builtin_amdgcn_global_load_lds(
      (const __attribute__((address_space(1))) unsigned int*)g,
      (__attribute__((address_space(3))) unsigned int*)l, 16, 0, 0);
}

__device__ __forceinline__ unsigned cvtpk(float lo, float hi) {
  unsigned r;
  asm("v_cvt_pk_bf16_f32 %0, %1, %2" : "=v"(r) : "v"(lo), "v"(hi));
  return r;
}
__device__ __forceinline__ void swap32(unsigned& a, unsigned& b) {
  asm("v_permlane32_swap_b32 %0, %1" : "+v"(a), "+v"(b));
}

#define MFMA16(a, b, c) __builtin_amdgcn_mfma_f32_16x16x32_bf16((a), (b), (c), 0, 0, 0)
#define MFMA32(a, b, c) __builtin_amdgcn_mfma_f32_32x32x16_bf16((a), (b), (c), 0, 0, 0)

// ---------------- prep kernels ----------------

__global__ __launch_bounds__(256) void k_convert_f32_bf16(const float* __restrict__ in,
                                                          u16* __restrict__ out, int n4) {
  int i = blockIdx.x * 256 + threadIdx.x;
  if (i >= n4) return;
  float4 v = ((const float4*)in)[i];
  ushort4 o;
  o.x = f2bf(v.x); o.y = f2bf(v.y); o.z = f2bf(v.z); o.w = f2bf(v.w);
  ((ushort4*)out)[i] = o;
}

// all 4 weight transposes in one launch. out[C][R] = bf16(in[R][C]).
__global__ __launch_bounds__(256) void k_transpose_all(const float* __restrict__ wq,
                                                       const float* __restrict__ wk,
                                                       const float* __restrict__ wv,
                                                       const float* __restrict__ wo,
                                                       u16* __restrict__ Wqkvt,
                                                       u16* __restrict__ Wot) {
  __shared__ float tile[32][33];
  int fb = blockIdx.x;
  const float* in;
  u16* out;
  int R, C, bxi, byi;
  if (fb < 8192) {              // wq: [2048][4096] -> Wqkvt rows 0..4095
    in = wq; out = Wqkvt; R = 2048; C = 4096;
    bxi = fb & 127; byi = fb >> 7;
  } else if (fb < 10240) {      // wk: [2048][1024] -> rows 4096..5119
    in = wk; out = Wqkvt + 4096 * 2048; R = 2048; C = 1024;
    int l = fb - 8192; bxi = l & 31; byi = l >> 5;
  } else if (fb < 12288) {      // wv: [2048][1024] -> rows 5120..6143
    in = wv; out = Wqkvt + 5120 * 2048; R = 2048; C = 1024;
    int l = fb - 10240; bxi = l & 31; byi = l >> 5;
  } else {                      // wo: [4096][2048] -> Wot [2048][4096]
    in = wo; out = Wot; R = 4096; C = 2048;
    int l = fb - 12288; bxi = l & 63; byi = l >> 6;
  }
  int tx = threadIdx.x & 31, ty = threadIdx.x >> 5;
  int bx = bxi * 32, by = byi * 32;
#pragma unroll
  for (int i = 0; i < 4; i++)
    tile[ty + i * 8][tx] = in[(size_t)(by + ty + i * 8) * C + bx + tx];
  __syncthreads();
#pragma unroll
  for (int i = 0; i < 4; i++)
    out[(size_t)(bx + ty + i * 8) * R + by + tx] = f2bf(tile[tx][ty + i * 8]);
}

// out[col][row] = in[row][col]; in row-stride C, out row-stride R
__global__ __launch_bounds__(256) void k_transpose_bf16(const u16* __restrict__ in,
                                                        u16* __restrict__ out, int R, int C) {
  __shared__ u16 tile[32][33];
  int tx = threadIdx.x, ty = threadIdx.y;
  int bx = blockIdx.x * 32, by = blockIdx.y * 32;
#pragma unroll
  for (int i = 0; i < 4; i++)
    tile[ty + i * 8][tx] = in[(size_t)(by + ty + i * 8) * C + bx + tx];
  __syncthreads();
#pragma unroll
  for (int i = 0; i < 4; i++)
    out[(size_t)(bx + ty + i * 8) * R + by + tx] = tile[tx][ty + i * 8];
}

// ---------------- RoPE cos/sin table: tab[row][i] = (cos, sin) ----------------
// 4096 rows x 128 i = 4 MB. All device trig confined here (~6 us).
__global__ __launch_bounds__(256) void k_ropetab(const int* __restrict__ pos,
                                                 float2* __restrict__ tab) {
  int idx = blockIdx.x * 256 + threadIdx.x;  // 524288 total
  int i = idx & 127, row = idx >> 7;
  float p = (float)pos[row];
  float f = p * exp2f((float)i * (-13.287712379549449f / 128.f));
  float sn, cs;
  sincosf(f, &sn, &cs);
  tab[idx] = make_float2(cs, sn);
}

// ---------------- GEMM m97-style (kept for out-proj) ----------------

template <int OUT_BF16>
__global__ __launch_bounds__(256) void k_gemm_bt(const u16* __restrict__ A,
                                                 const u16* __restrict__ Bt,
                                                 void* __restrict__ C, int M, int N, int K) {
  __shared__ u16 As[128 * 64];
  __shared__ u16 Bs[128 * 64];
  const int tid = threadIdx.x;
  const int lane = tid & 63;
  const int w = tid >> 6;
  const int l15 = lane & 15, l4 = lane >> 4;
  const int wr = w >> 1, wc = w & 1;
  const int bx = blockIdx.x, by = blockIdx.y;

  f32x4 acc[4][4];
#pragma unroll
  for (int a = 0; a < 4; a++)
#pragma unroll
    for (int b2 = 0; b2 < 4; b2++) acc[a][b2] = (f32x4){0.f, 0.f, 0.f, 0.f};

  const u16* Abase = A + (size_t)by * 128 * K;
  const u16* Bbase = Bt + (size_t)bx * 128 * K;

  for (int kk = 0; kk < K; kk += 64) {
    __syncthreads();
#pragma unroll
    for (int j = 0; j < 4; j++) {
      int ci = w * 256 + j * 64 + lane;
      int row = ci >> 3, c = ci & 7;
      gload16(Abase + (size_t)row * K + kk + c * 8, (char*)As + ci * 16);
      gload16(Bbase + (size_t)row * K + kk + c * 8, (char*)Bs + ci * 16);
    }
    __syncthreads();
#pragma unroll
    for (int kc = 0; kc < 2; kc++) {
      int kb = kc * 64 + l4 * 16;
      bf16x8 av[4], bv[4];
#pragma unroll
      for (int mt = 0; mt < 4; mt++)
        av[mt] = *(const bf16x8*)((const char*)As + (wr * 64 + mt * 16 + l15) * 128 + kb);
#pragma unroll
      for (int nt = 0; nt < 4; nt++)
        bv[nt] = *(const bf16x8*)((const char*)Bs + (wc * 64 + nt * 16 + l15) * 128 + kb);
#pragma unroll
      for (int mt = 0; mt < 4; mt++)
#pragma unroll
        for (int nt = 0; nt < 4; nt++) acc[mt][nt] = MFMA16(av[mt], bv[nt], acc[mt][nt]);
    }
  }
#pragma unroll
  for (int mt = 0; mt < 4; mt++) {
#pragma unroll
    for (int nt = 0; nt < 4; nt++) {
      int col = bx * 128 + wc * 64 + nt * 16 + l15;
#pragma unroll
      for (int r = 0; r < 4; r++) {
        int row = by * 128 + wr * 64 + mt * 16 + l4 * 4 + r;
        if (OUT_BF16)
          ((u16*)C)[(size_t)row * N + col] = f2bf(acc[mt][nt][r]);
        else
          ((float*)C)[(size_t)row * N + col] = acc[mt][nt][r];
      }
    }
  }
}

// ---------------- GEMM 256x256 8-phase + fused RoPE epilogue ----------------
// Main loop identical to r10 (race-safe). Epilogue: for head-tiles bx<20
// (16 Q + 4 K heads; BN=256 == head width so bx == head), rope pair (d,d+128)
// lives in partner wave wc^2 == thread tid^128 with identical (lane,wr,i,j,r).
// Exchange acc via the (dead) 128 KB staging LDS in 2 chunks of 4 row-tiles.

__global__ __launch_bounds__(512, 1) void k_gemm256(const u16* __restrict__ A,
                                                    const u16* __restrict__ Bt,
                                                    u16* __restrict__ C, int N, int K,
                                                    const float2* __restrict__ tab) {
  extern __shared__ char smem[];
  const int tid = threadIdx.x;
  const int lane = tid & 63, w = tid >> 6;
  const int l15 = lane & 15, l4 = lane >> 4;
  const int wr = w >> 2, wc = w & 3;
  const int bx = blockIdx.x, by = blockIdx.y;
  const int NT = K >> 6;

  const u16* Ab = A + (size_t)(by * 256) * K;
  const u16* Bb = Bt + (size_t)(bx * 256) * K;

  int srcoff[2], dstoff[2];
#pragma unroll
  for (int rr = 0; rr < 2; rr++) {
    int ci = rr * 512 + tid;
    int lc = ci ^ (((ci >> 5) & 1) << 1);
    int kc = lc >> 9, row = (lc >> 2) & 127, g2 = lc & 3;
    srcoff[rr] = row * K + kc * 32 + g2 * 8;
    dstoff[rr] = ci * 16;
  }

  auto SH = [&](int Tg, int halfidx) {
    const u16* base = (halfidx < 2) ? (Ab + (size_t)(halfidx * 128) * K)
                                    : (Bb + (size_t)((halfidx - 2) * 128) * K);
    char* dst = smem + (Tg & 1) * 65536 + halfidx * 16384;
    int kk = Tg * 64;
#pragma unroll
    for (int rr = 0; rr < 2; rr++)
      gload16(base + srcoff[rr] + kk, dst + dstoff[rr]);
  };

  auto lda = [&](int c, int kc, int mrow4) -> bf16x8 {
    int L = kc * 8192 + (mrow4 * 16 + l15) * 64 + l4 * 16;
    int P = L ^ (((L >> 9) & 1) << 5);
    return *(const bf16x8*)(smem + c * 65536 + wr * 16384 + P);
  };
  auto ldb = [&](int c, int kc, int j) -> bf16x8 {
    int L = kc * 8192 + ((wc & 1) * 64 + j * 16 + l15) * 64 + l4 * 16;
    int P = L ^ (((L >> 9) & 1) << 5);
    return *(const bf16x8*)(smem + c * 65536 + 32768 + (wc >> 1) * 16384 + P);
  };

  f32x4 acc[8][4];
#pragma unroll
  for (int i = 0; i < 8; i++)
#pragma unroll
    for (int j = 0; j < 4; j++) acc[i][j] = (f32x4){0.f, 0.f, 0.f, 0.f};

  SH(0, 0); SH(0, 1); SH(0, 2); SH(0, 3);
  SH(1, 2); SH(1, 3);
  asm volatile("s_waitcnt vmcnt(4)" ::: "memory");
  __builtin_amdgcn_s_barrier();
  asm volatile("" ::: "memory");

  bf16x8 bv[2][4];
  for (int T = 0; T < NT; ++T) {
    const int c = T & 1;
#pragma unroll
    for (int q = 0; q < 4; q++) {
      const int kc = q & 1, mh = q >> 1;
      bf16x8 av[4];
      if (q < 2) {
#pragma unroll
        for (int j = 0; j < 4; j++) bv[kc][j] = ldb(c, kc, j);
      }
#pragma unroll
      for (int ii = 0; ii < 4; ii++) av[ii] = lda(c, kc, mh * 4 + ii);
      if (q == 0)      { if (T + 1 < NT) SH(T + 1, 0); }
      else if (q == 1) { if (T + 1 < NT) SH(T + 1, 1); }
      else if (q == 2) { if (T + 2 < NT) SH(T + 2, 2); }
      else             { if (T + 2 < NT) SH(T + 2, 3); }
      if (q == 3) {
        if (T < NT - 2)       asm volatile("s_waitcnt vmcnt(4)" ::: "memory");
        else if (T == NT - 2) asm volatile("s_waitcnt vmcnt(0)" ::: "memory");
      }
      asm volatile("" ::: "memory");
      __builtin_amdgcn_s_barrier();
      asm volatile("" ::: "memory");
      asm volatile("s_waitcnt lgkmcnt(0)" ::: "memory");
      __builtin_amdgcn_sched_barrier(0);
      __builtin_amdgcn_s_setprio(1);
#pragma unroll
      for (int ii = 0; ii < 4; ii++)
#pragma unroll
        for (int j = 0; j < 4; j++)
          acc[mh * 4 + ii][j] = MFMA16(av[ii], bv[kc][j], acc[mh * 4 + ii][j]);
      __builtin_amdgcn_s_setprio(0);
      asm volatile("" ::: "memory");
      __builtin_amdgcn_s_barrier();
      asm volatile("" ::: "memory");
    }
  }

  if (bx < 20) {
    // ---- fused RoPE epilogue (Q + K heads) ----
    float* X = (float*)smem;
    const float sgn = (wc < 2) ? -1.f : 1.f;
    const int ptid = tid ^ 128;  // partner wave: wc ^= 2, same wr/lane
#pragma unroll
    for (int ih = 0; ih < 2; ih++) {
      __syncthreads();  // LDS safe: main-loop reads done / prev chunk read done
#pragma unroll
      for (int i2 = 0; i2 < 4; i2++)
#pragma unroll
        for (int j2 = 0; j2 < 4; j2++)
#pragma unroll
          for (int r2 = 0; r2 < 4; r2++)
            X[tid * 64 + i2 * 16 + j2 * 4 + r2] = acc[ih * 4 + i2][j2][r2];
      __syncthreads();
#pragma unroll
      for (int i2 = 0; i2 < 4; i2++) {
#pragma unroll
        for (int j2 = 0; j2 < 4; j2++) {
          int col = bx * 256 + wc * 64 + j2 * 16 + l15;
          int ti = (wc & 1) * 64 + j2 * 16 + l15;  // freq index (same both halves)
#pragma unroll
          for (int r2 = 0; r2 < 4; r2++) {
            int row = by * 256 + wr * 128 + (ih * 4 + i2) * 16 + l4 * 4 + r2;
            float mine = acc[ih * 4 + i2][j2][r2];
            float part = X[ptid * 64 + i2 * 16 + j2 * 4 + r2];
            float2 t = tab[(size_t)row * 128 + ti];
            C[(size_t)row * N + col] = f2bf(mine * t.x + sgn * part * t.y);
          }
        }
      }
    }
  } else {
    // ---- plain epilogue (V heads / generic) ----
#pragma unroll
    for (int i = 0; i < 8; i++) {
#pragma unroll
      for (int j = 0; j < 4; j++) {
        int col = bx * 256 + wc * 64 + j * 16 + l15;
#pragma unroll
        for (int r = 0; r < 4; r++) {
          int row = by * 256 + wr * 128 + i * 16 + l4 * 4 + r;
          C[(size_t)row * N + col] = f2bf(acc[i][j][r]);
        }
      }
    }
  }
}

// ---------------- flash attention (byte-identical to r10/r16's 226 us kernel) ----------------

__shared__ __align__(16) u16 aK0[8192];
__shared__ __align__(16) u16 aK1[8192];
__shared__ __align__(16) u16 aV0[8192];
__shared__ __align__(16) u16 aV1[8192];

__global__ __launch_bounds__(256, 2) void k_attn(const u16* __restrict__ QKV,
                                                 const u16* __restrict__ Vt,
                                                 u16* __restrict__ AO) {
  const int tid = threadIdx.x, lane = tid & 63, w = tid >> 6;
  const int r31 = lane & 31, hi = lane >> 5;

  const int flat = blockIdx.x;
  const int r = flat & 7;            // XCD (round-robin dispatch)
  const int idx = flat >> 3;
  const int b = r >> 2, kv = r & 3;  // one (b,kv) per XCD: 2 MB K/V, L2-resident
  const int half = idx >> 5, j = idx & 31;
  const int qb = half ? 15 - (j >> 1) : (j >> 1);
  const int h = kv * 4 + (j & 1) + 2 * half;

  bf16x8 qreg[16];
  {
    const u16* qp = QKV + (size_t)(b * 2048 + qb * 128 + w * 32 + r31) * QKVS + h * 256 + hi * 8;
#pragma unroll
    for (int kc = 0; kc < 16; kc++) qreg[kc] = *(const bf16x8*)(qp + kc * 16);
  }

  f32x16 o[8];
#pragma unroll
  for (int df = 0; df < 8; df++)
#pragma unroll
    for (int jj = 0; jj < 16; jj++) o[df][jj] = 0.f;
  float mrow = -3e38f, lrow = 0.f;

  const int nt = 4 * qb + 4;  // always even
  const int tlim = 4 * qb + w;
  const int qloc = qb * 128 + w * 32 + r31;
  const u16* Kbase = QKV + (size_t)(b * 2048) * QKVS + 4096 + kv * 256;
  const u16* Vbase = Vt + (size_t)(kv * 256) * 4096 + b * 2048;

  int kfix[4], vfix[4];
#pragma unroll
  for (int jj = 0; jj < 4; jj++) {
    int ci = jj * 256 + tid;
    int krow = ci >> 5, kc = ci & 31;
    int kcg = (kc & 24) | ((kc ^ krow) & 7);
    kfix[jj] = krow * QKVS + kcg * 8;
    int vrow = ci >> 2, vc = ci & 3;
    int vg = (vc - (vrow >> 1)) & 3;
    vfix[jj] = vrow * 4096 + vg * 8;
  }
  int koff = 0, voff = 0;

  auto STAGE = [&](u16* Kd, u16* Vd) {
#pragma unroll
    for (int jj = 0; jj < 4; jj++)
      gload16(Kbase + kfix[jj] + koff, (char*)Kd + (jj * 256 + tid) * 16);
#pragma unroll
    for (int jj = 0; jj < 4; jj++)
      gload16(Vbase + vfix[jj] + voff, (char*)Vd + (jj * 256 + tid) * 16);
    koff += 32 * QKVS;
    voff += 32;
  };

  auto COMPUTE = [&](int t, const u16* Kc, const u16* Vc) {
    f32x16 s;
#pragma unroll
    for (int jj = 0; jj < 16; jj++) s[jj] = 0.f;
#pragma unroll
    for (int kc = 0; kc < 16; kc++) {
      int ch = kc * 2 + hi;
      int cs = (ch & 24) | ((ch ^ r31) & 7);
      bf16x8 kf = *(const bf16x8*)((const char*)Kc + r31 * 512 + cs * 16);
      s = MFMA32(kf, qreg[kc], s);
    }

    const float C = 0.0625f * LOG2E;
    float z[16];
#pragma unroll
    for (int jj = 0; jj < 16; jj++) z[jj] = s[jj] * C;
    if (t == tlim) {
#pragma unroll
      for (int jj = 0; jj < 16; jj++) {
        int kvg = t * 32 + (jj & 3) + 8 * (jj >> 2) + 4 * hi;
        if (kvg > qloc) z[jj] = -1e30f;
      }
    }

    float m0 = z[0];
#pragma unroll
    for (int jj = 1; jj < 16; jj++) m0 = fmaxf(m0, z[jj]);
    m0 = fmaxf(m0, __shfl_xor(m0, 32));
    if (__any(m0 > mrow + 11.54f)) {  // rare after first tile
      float mn = fmaxf(mrow, m0);
      float alpha = exp2f(mrow - mn);
      mrow = mn;
      lrow *= alpha;
#pragma unroll
      for (int jj = 0; jj < 16; jj++) {
        float a = __shfl(alpha, (jj & 3) + 8 * (jj >> 2) + 4 * hi);
#pragma unroll
        for (int df = 0; df < 8; df++) o[df][jj] *= a;
      }
    }
    float sum = 0.f;
#pragma unroll
    for (int jj = 0; jj < 16; jj++) {
      z[jj] = exp2f(z[jj] - mrow);
      sum += z[jj];
    }
    sum += __shfl_xor(sum, 32);
    lrow += sum;

    unsigned a0 = cvtpk(z[0], z[1]), a2 = cvtpk(z[4], z[5]);
    swap32(a0, a2);
    unsigned a1 = cvtpk(z[2], z[3]), a3 = cvtpk(z[6], z[7]);
    swap32(a1, a3);
    unsigned b0 = cvtpk(z[8], z[9]), b2 = cvtpk(z[12], z[13]);
    swap32(b0, b2);
    unsigned b1 = cvtpk(z[10], z[11]), b3 = cvtpk(z[14], z[15]);
    swap32(b1, b3);
    union UU { unsigned u[4]; bf16x8 v; };
    UU ua; ua.u[0] = a0; ua.u[1] = a1; ua.u[2] = a2; ua.u[3] = a3;
    UU ub; ub.u[0] = b0; ub.u[1] = b1; ub.u[2] = b2; ub.u[3] = b3;
    bf16x8 pa0 = ua.v, pa1 = ub.v;

#pragma unroll
    for (int df = 0; df < 8; df++) {
      int vr = df * 32 + r31;
      int c0 = (hi + (vr >> 1)) & 3;
      int c1 = (2 + hi + (vr >> 1)) & 3;
      bf16x8 v0 = *(const bf16x8*)((const char*)Vc + vr * 64 + c0 * 16);
      bf16x8 v1 = *(const bf16x8*)((const char*)Vc + vr * 64 + c1 * 16);
      o[df] = MFMA32(pa0, v0, o[df]);
      o[df] = MFMA32(pa1, v1, o[df]);
    }
  };

  STAGE(aK0, aV0);
  __syncthreads();

  for (int t = 0; t < nt; t += 2) {
    STAGE(aK1, aV1);
    if (t <= tlim) COMPUTE(t, aK0, aV0);
    __syncthreads();
    if (t + 2 < nt) STAGE(aK0, aV0);
    if (t + 1 <= tlim) COMPUTE(t + 1, aK1, aV1);
    __syncthreads();
  }

  float rl = 1.f / lrow;
  size_t rowbase = (size_t)(b * 2048 + qb * 128 + w * 32);
#pragma unroll
  for (int jj = 0; jj < 16; jj++) {
    float rr2 = __shfl(rl, (jj & 3) + 8 * (jj >> 2) + 4 * hi);
    int qr = (jj & 3) + 8 * (jj >> 2) + 4 * hi;
#pragma unroll
    for (int df = 0; df < 8; df++)
      AO[(rowbase + qr) * 4096 + h * 256 + df * 32 + r31] = f2bf(o[df][jj] * rr2);
  }
}

// ---------------- host ----------------

// ws layout (bytes), high-water 113.2 MB:
// Xb @0 (16MB, dead after QKV gemm) -- AO @0 (32MB) aliases it + Wqkvt head.
// Wqkvt @16.7M (24MB), dead after gemm. Vt @33.5M (8MB) aliases Wqkvt tail.
// Wot @41.9M (16MB, persists). QKV @58.7M (48MB). TAB @109.1M (4MB).
#define OFF_AO    0u
#define OFF_XB    0u
#define OFF_WQKVT 16777216u
#define OFF_VT    33554432u
#define OFF_WOT   41943040u
#define OFF_QKV   58720256u
#define OFF_TAB   109051904u

extern "C" void kernel_launch(void* const* d_in, const int* in_sizes, int n_in,
                              void* d_out, int out_size, void* d_ws, size_t ws_size,
                              hipStream_t stream) {
  const float* hs = (const float*)d_in[0];
  const int* pos = (const int*)d_in[1];
  const float* wq = (const float*)d_in[2];
  const float* wk = (const float*)d_in[3];
  const float* wv = (const float*)d_in[4];
  const float* wo = (const float*)d_in[5];
  float* out = (float*)d_out;
  char* ws = (char*)d_ws;

  u16* Xb    = (u16*)(ws + OFF_XB);
  u16* Wqkvt = (u16*)(ws + OFF_WQKVT);
  u16* Vt    = (u16*)(ws + OFF_VT);
  u16* Wot   = (u16*)(ws + OFF_WOT);
  u16* QKV   = (u16*)(ws + OFF_QKV);
  float2* Tab = (float2*)(ws + OFF_TAB);
  u16* AO    = (u16*)(ws + OFF_AO);

  dim3 tb(32, 8);

  // rope cos/sin table (only place with device trig; consumed by gemm256 epilogue)
  k_ropetab<<<2048, 256, 0, stream>>>(pos, Tab);

  // prep: convert + all weight transposes (one launch)
  k_convert_f32_bf16<<<8192, 256, 0, stream>>>(hs, Xb, 2097152);
  k_transpose_all<<<20480, 256, 0, stream>>>(wq, wk, wv, wo, Wqkvt, Wot);

  // fused QKV projection + RoPE epilogue (Q/K heads rope'd in-register)
  (void)hipFuncSetAttribute((const void*)k_gemm256,
                            hipFuncAttributeMaxDynamicSharedMemorySize, 131072);
  k_gemm256<<<dim3(24, 16), 512, 131072, stream>>>(Xb, Wqkvt, QKV, 6144, 2048, Tab);

  // V^T (V = cols 5120..6143) -> Vt [1024][4096]
  k_transpose_bf16<<<dim3(32, 128), tb, 0, stream>>>(QKV + 5120, Vt, 4096, QKVS);

  // flash attention (r10 kernel: no table, XCD-pinned, L2-resident K/V)
  k_attn<<<dim3(512), 256, 0, stream>>>(QKV, Vt, AO);

  // output projection (fp32 out), m97 structure
  k_gemm_bt<0><<<dim3(16, 32), 256, 0, stream>>>(AO, Wot, out, 4096, 2048, 4096);
}

// Round 18
// 466.918 us; speedup vs baseline: 1.1847x; 1.1847x over previous
//
#include <hip/hip_runtime.h>

typedef unsigned short u16;
typedef __bf16 bf16_t;
typedef bf16_t bf16x8 __attribute__((ext_vector_type(8)));
typedef float f32x4 __attribute__((ext_vector_type(4)));
typedef float f32x16 __attribute__((ext_vector_type(16)));

#define LOG2E 1.4426950408889634f
#define QKVS 6144  // row stride of fused QKV activation buffer

__device__ __forceinline__ u16 f2bf(float f) {
  union { float f; unsigned u; } c; c.f = f;
  unsigned r = c.u + 0x7fffu + ((c.u >> 16) & 1u);
  return (u16)(r >> 16);
}
__device__ __forceinline__ float bf2f(u16 u) {
  union { unsigned u; float f; } c; c.u = ((unsigned)u) << 16;
  return c.f;
}

__device__ __forceinline__ void gload16(const void* g, void* l) {
  __builtin_amdgcn_global_load_lds(
      (const __attribute__((address_space(1))) unsigned int*)g,
      (__attribute__((address_space(3))) unsigned int*)l, 16, 0, 0);
}

__device__ __forceinline__ unsigned cvtpk(float lo, float hi) {
  unsigned r;
  asm("v_cvt_pk_bf16_f32 %0, %1, %2" : "=v"(r) : "v"(lo), "v"(hi));
  return r;
}
__device__ __forceinline__ void swap32(unsigned& a, unsigned& b) {
  asm("v_permlane32_swap_b32 %0, %1" : "+v"(a), "+v"(b));
}

#define MFMA16(a, b, c) __builtin_amdgcn_mfma_f32_16x16x32_bf16((a), (b), (c), 0, 0, 0)
#define MFMA32(a, b, c) __builtin_amdgcn_mfma_f32_32x32x16_bf16((a), (b), (c), 0, 0, 0)

// ---------------- prep kernels ----------------

__global__ __launch_bounds__(256) void k_convert_f32_bf16(const float* __restrict__ in,
                                                          u16* __restrict__ out, int n4) {
  int i = blockIdx.x * 256 + threadIdx.x;
  if (i >= n4) return;
  float4 v = ((const float4*)in)[i];
  ushort4 o;
  o.x = f2bf(v.x); o.y = f2bf(v.y); o.z = f2bf(v.z); o.w = f2bf(v.w);
  ((ushort4*)out)[i] = o;
}

// all 4 weight transposes in one launch. out[C][R] = bf16(in[R][C]).
__global__ __launch_bounds__(256) void k_transpose_all(const float* __restrict__ wq,
                                                       const float* __restrict__ wk,
                                                       const float* __restrict__ wv,
                                                       const float* __restrict__ wo,
                                                       u16* __restrict__ Wqkvt,
                                                       u16* __restrict__ Wot) {
  __shared__ float tile[32][33];
  int fb = blockIdx.x;
  const float* in;
  u16* out;
  int R, C, bxi, byi;
  if (fb < 8192) {              // wq: [2048][4096] -> Wqkvt rows 0..4095
    in = wq; out = Wqkvt; R = 2048; C = 4096;
    bxi = fb & 127; byi = fb >> 7;
  } else if (fb < 10240) {      // wk: [2048][1024] -> rows 4096..5119
    in = wk; out = Wqkvt + 4096 * 2048; R = 2048; C = 1024;
    int l = fb - 8192; bxi = l & 31; byi = l >> 5;
  } else if (fb < 12288) {      // wv: [2048][1024] -> rows 5120..6143
    in = wv; out = Wqkvt + 5120 * 2048; R = 2048; C = 1024;
    int l = fb - 10240; bxi = l & 31; byi = l >> 5;
  } else {                      // wo: [4096][2048] -> Wot [2048][4096]
    in = wo; out = Wot; R = 4096; C = 2048;
    int l = fb - 12288; bxi = l & 63; byi = l >> 6;
  }
  int tx = threadIdx.x & 31, ty = threadIdx.x >> 5;
  int bx = bxi * 32, by = byi * 32;
#pragma unroll
  for (int i = 0; i < 4; i++)
    tile[ty + i * 8][tx] = in[(size_t)(by + ty + i * 8) * C + bx + tx];
  __syncthreads();
#pragma unroll
  for (int i = 0; i < 4; i++)
    out[(size_t)(bx + ty + i * 8) * R + by + tx] = f2bf(tile[tx][ty + i * 8]);
}

// out[col][row] = in[row][col]; in row-stride C, out row-stride R
__global__ __launch_bounds__(256) void k_transpose_bf16(const u16* __restrict__ in,
                                                        u16* __restrict__ out, int R, int C) {
  __shared__ u16 tile[32][33];
  int tx = threadIdx.x, ty = threadIdx.y;
  int bx = blockIdx.x * 32, by = blockIdx.y * 32;
#pragma unroll
  for (int i = 0; i < 4; i++)
    tile[ty + i * 8][tx] = in[(size_t)(by + ty + i * 8) * C + bx + tx];
  __syncthreads();
#pragma unroll
  for (int i = 0; i < 4; i++)
    out[(size_t)(bx + ty + i * 8) * R + by + tx] = tile[tx][ty + i * 8];
}

// ---------------- RoPE cos/sin table: tab[row][i] = (cos, sin) ----------------
__global__ __launch_bounds__(256) void k_ropetab(const int* __restrict__ pos,
                                                 float2* __restrict__ tab) {
  int idx = blockIdx.x * 256 + threadIdx.x;  // 524288 total
  int i = idx & 127, row = idx >> 7;
  float p = (float)pos[row];
  float f = p * exp2f((float)i * (-13.287712379549449f / 128.f));
  float sn, cs;
  sincosf(f, &sn, &cs);
  tab[idx] = make_float2(cs, sn);
}

// ---------------- GEMM m97-style (kept for out-proj) ----------------

template <int OUT_BF16>
__global__ __launch_bounds__(256) void k_gemm_bt(const u16* __restrict__ A,
                                                 const u16* __restrict__ Bt,
                                                 void* __restrict__ C, int M, int N, int K) {
  __shared__ u16 As[128 * 64];
  __shared__ u16 Bs[128 * 64];
  const int tid = threadIdx.x;
  const int lane = tid & 63;
  const int w = tid >> 6;
  const int l15 = lane & 15, l4 = lane >> 4;
  const int wr = w >> 1, wc = w & 1;
  const int bx = blockIdx.x, by = blockIdx.y;

  f32x4 acc[4][4];
#pragma unroll
  for (int a = 0; a < 4; a++)
#pragma unroll
    for (int b2 = 0; b2 < 4; b2++) acc[a][b2] = (f32x4){0.f, 0.f, 0.f, 0.f};

  const u16* Abase = A + (size_t)by * 128 * K;
  const u16* Bbase = Bt + (size_t)bx * 128 * K;

  for (int kk = 0; kk < K; kk += 64) {
    __syncthreads();
#pragma unroll
    for (int j = 0; j < 4; j++) {
      int ci = w * 256 + j * 64 + lane;
      int row = ci >> 3, c = ci & 7;
      gload16(Abase + (size_t)row * K + kk + c * 8, (char*)As + ci * 16);
      gload16(Bbase + (size_t)row * K + kk + c * 8, (char*)Bs + ci * 16);
    }
    __syncthreads();
#pragma unroll
    for (int kc = 0; kc < 2; kc++) {
      int kb = kc * 64 + l4 * 16;
      bf16x8 av[4], bv[4];
#pragma unroll
      for (int mt = 0; mt < 4; mt++)
        av[mt] = *(const bf16x8*)((const char*)As + (wr * 64 + mt * 16 + l15) * 128 + kb);
#pragma unroll
      for (int nt = 0; nt < 4; nt++)
        bv[nt] = *(const bf16x8*)((const char*)Bs + (wc * 64 + nt * 16 + l15) * 128 + kb);
#pragma unroll
      for (int mt = 0; mt < 4; mt++)
#pragma unroll
        for (int nt = 0; nt < 4; nt++) acc[mt][nt] = MFMA16(av[mt], bv[nt], acc[mt][nt]);
    }
  }
#pragma unroll
  for (int mt = 0; mt < 4; mt++) {
#pragma unroll
    for (int nt = 0; nt < 4; nt++) {
      int col = bx * 128 + wc * 64 + nt * 16 + l15;
#pragma unroll
      for (int r = 0; r < 4; r++) {
        int row = by * 128 + wr * 64 + mt * 16 + l4 * 4 + r;
        if (OUT_BF16)
          ((u16*)C)[(size_t)row * N + col] = f2bf(acc[mt][nt][r]);
        else
          ((float*)C)[(size_t)row * N + col] = acc[mt][nt][r];
      }
    }
  }
}

// ---------------- GEMM 256x256 8-phase + fused RoPE epilogue (conflict-free) ----------------
// Main loop identical to r10 (race-safe). Epilogue exchange: float4 element-
// major / thread-minor layout X4[eb*512 + tid] (16 x 512 x 16B = 128 KB) ->
// every ds_write_b128/ds_read_b128 has lanes at consecutive 16B addresses
// (conflict-free; r17's X[tid*64+e] was 64-way conflicted, 40.6M conflicts).

__global__ __launch_bounds__(512, 1) void k_gemm256(const u16* __restrict__ A,
                                                    const u16* __restrict__ Bt,
                                                    u16* __restrict__ C, int N, int K,
                                                    const float2* __restrict__ tab) {
  extern __shared__ char smem[];
  const int tid = threadIdx.x;
  const int lane = tid & 63, w = tid >> 6;
  const int l15 = lane & 15, l4 = lane >> 4;
  const int wr = w >> 2, wc = w & 3;
  const int bx = blockIdx.x, by = blockIdx.y;
  const int NT = K >> 6;

  const u16* Ab = A + (size_t)(by * 256) * K;
  const u16* Bb = Bt + (size_t)(bx * 256) * K;

  int srcoff[2], dstoff[2];
#pragma unroll
  for (int rr = 0; rr < 2; rr++) {
    int ci = rr * 512 + tid;
    int lc = ci ^ (((ci >> 5) & 1) << 1);
    int kc = lc >> 9, row = (lc >> 2) & 127, g2 = lc & 3;
    srcoff[rr] = row * K + kc * 32 + g2 * 8;
    dstoff[rr] = ci * 16;
  }

  auto SH = [&](int Tg, int halfidx) {
    const u16* base = (halfidx < 2) ? (Ab + (size_t)(halfidx * 128) * K)
                                    : (Bb + (size_t)((halfidx - 2) * 128) * K);
    char* dst = smem + (Tg & 1) * 65536 + halfidx * 16384;
    int kk = Tg * 64;
#pragma unroll
    for (int rr = 0; rr < 2; rr++)
      gload16(base + srcoff[rr] + kk, dst + dstoff[rr]);
  };

  auto lda = [&](int c, int kc, int mrow4) -> bf16x8 {
    int L = kc * 8192 + (mrow4 * 16 + l15) * 64 + l4 * 16;
    int P = L ^ (((L >> 9) & 1) << 5);
    return *(const bf16x8*)(smem + c * 65536 + wr * 16384 + P);
  };
  auto ldb = [&](int c, int kc, int j) -> bf16x8 {
    int L = kc * 8192 + ((wc & 1) * 64 + j * 16 + l15) * 64 + l4 * 16;
    int P = L ^ (((L >> 9) & 1) << 5);
    return *(const bf16x8*)(smem + c * 65536 + 32768 + (wc >> 1) * 16384 + P);
  };

  f32x4 acc[8][4];
#pragma unroll
  for (int i = 0; i < 8; i++)
#pragma unroll
    for (int j = 0; j < 4; j++) acc[i][j] = (f32x4){0.f, 0.f, 0.f, 0.f};

  SH(0, 0); SH(0, 1); SH(0, 2); SH(0, 3);
  SH(1, 2); SH(1, 3);
  asm volatile("s_waitcnt vmcnt(4)" ::: "memory");
  __builtin_amdgcn_s_barrier();
  asm volatile("" ::: "memory");

  bf16x8 bv[2][4];
  for (int T = 0; T < NT; ++T) {
    const int c = T & 1;
#pragma unroll
    for (int q = 0; q < 4; q++) {
      const int kc = q & 1, mh = q >> 1;
      bf16x8 av[4];
      if (q < 2) {
#pragma unroll
        for (int j = 0; j < 4; j++) bv[kc][j] = ldb(c, kc, j);
      }
#pragma unroll
      for (int ii = 0; ii < 4; ii++) av[ii] = lda(c, kc, mh * 4 + ii);
      if (q == 0)      { if (T + 1 < NT) SH(T + 1, 0); }
      else if (q == 1) { if (T + 1 < NT) SH(T + 1, 1); }
      else if (q == 2) { if (T + 2 < NT) SH(T + 2, 2); }
      else             { if (T + 2 < NT) SH(T + 2, 3); }
      if (q == 3) {
        if (T < NT - 2)       asm volatile("s_waitcnt vmcnt(4)" ::: "memory");
        else if (T == NT - 2) asm volatile("s_waitcnt vmcnt(0)" ::: "memory");
      }
      asm volatile("" ::: "memory");
      __builtin_amdgcn_s_barrier();
      asm volatile("" ::: "memory");
      asm volatile("s_waitcnt lgkmcnt(0)" ::: "memory");
      __builtin_amdgcn_sched_barrier(0);
      __builtin_amdgcn_s_setprio(1);
#pragma unroll
      for (int ii = 0; ii < 4; ii++)
#pragma unroll
        for (int j = 0; j < 4; j++)
          acc[mh * 4 + ii][j] = MFMA16(av[ii], bv[kc][j], acc[mh * 4 + ii][j]);
      __builtin_amdgcn_s_setprio(0);
      asm volatile("" ::: "memory");
      __builtin_amdgcn_s_barrier();
      asm volatile("" ::: "memory");
    }
  }

  if (bx < 20) {
    // ---- fused RoPE epilogue (Q + K heads), conflict-free float4 exchange ----
    float4* X4 = (float4*)smem;
    const float sgn = (wc < 2) ? -1.f : 1.f;
    const int ptid = tid ^ 128;  // partner wave: wc ^= 2, same wr/lane
#pragma unroll
    for (int ih = 0; ih < 2; ih++) {
      __syncthreads();  // prior LDS reads (main loop / prev chunk) complete
#pragma unroll
      for (int i2 = 0; i2 < 4; i2++)
#pragma unroll
        for (int j2 = 0; j2 < 4; j2++) {
          f32x4 a = acc[ih * 4 + i2][j2];
          X4[(i2 * 4 + j2) * 512 + tid] = make_float4(a[0], a[1], a[2], a[3]);
        }
      __syncthreads();
#pragma unroll
      for (int i2 = 0; i2 < 4; i2++) {
#pragma unroll
        for (int j2 = 0; j2 < 4; j2++) {
          int col = bx * 256 + wc * 64 + j2 * 16 + l15;
          int ti = (wc & 1) * 64 + j2 * 16 + l15;  // freq index (same both halves)
          float4 part = X4[(i2 * 4 + j2) * 512 + ptid];
          float pa[4] = {part.x, part.y, part.z, part.w};
#pragma unroll
          for (int r2 = 0; r2 < 4; r2++) {
            int row = by * 256 + wr * 128 + (ih * 4 + i2) * 16 + l4 * 4 + r2;
            float mine = acc[ih * 4 + i2][j2][r2];
            float2 t = tab[(size_t)row * 128 + ti];
            C[(size_t)row * N + col] = f2bf(mine * t.x + sgn * pa[r2] * t.y);
          }
        }
      }
    }
  } else {
    // ---- plain epilogue (V heads / generic) ----
#pragma unroll
    for (int i = 0; i < 8; i++) {
#pragma unroll
      for (int j = 0; j < 4; j++) {
        int col = bx * 256 + wc * 64 + j * 16 + l15;
#pragma unroll
        for (int r = 0; r < 4; r++) {
          int row = by * 256 + wr * 128 + i * 16 + l4 * 4 + r;
          C[(size_t)row * N + col] = f2bf(acc[i][j][r]);
        }
      }
    }
  }
}

// ---------------- flash attention (byte-identical to r10/r16's 226 us kernel) ----------------

__shared__ __align__(16) u16 aK0[8192];
__shared__ __align__(16) u16 aK1[8192];
__shared__ __align__(16) u16 aV0[8192];
__shared__ __align__(16) u16 aV1[8192];

__global__ __launch_bounds__(256, 2) void k_attn(const u16* __restrict__ QKV,
                                                 const u16* __restrict__ Vt,
                                                 u16* __restrict__ AO) {
  const int tid = threadIdx.x, lane = tid & 63, w = tid >> 6;
  const int r31 = lane & 31, hi = lane >> 5;

  const int flat = blockIdx.x;
  const int r = flat & 7;            // XCD (round-robin dispatch)
  const int idx = flat >> 3;
  const int b = r >> 2, kv = r & 3;  // one (b,kv) per XCD: 2 MB K/V, L2-resident
  const int half = idx >> 5, j = idx & 31;
  const int qb = half ? 15 - (j >> 1) : (j >> 1);
  const int h = kv * 4 + (j & 1) + 2 * half;

  bf16x8 qreg[16];
  {
    const u16* qp = QKV + (size_t)(b * 2048 + qb * 128 + w * 32 + r31) * QKVS + h * 256 + hi * 8;
#pragma unroll
    for (int kc = 0; kc < 16; kc++) qreg[kc] = *(const bf16x8*)(qp + kc * 16);
  }

  f32x16 o[8];
#pragma unroll
  for (int df = 0; df < 8; df++)
#pragma unroll
    for (int jj = 0; jj < 16; jj++) o[df][jj] = 0.f;
  float mrow = -3e38f, lrow = 0.f;

  const int nt = 4 * qb + 4;  // always even
  const int tlim = 4 * qb + w;
  const int qloc = qb * 128 + w * 32 + r31;
  const u16* Kbase = QKV + (size_t)(b * 2048) * QKVS + 4096 + kv * 256;
  const u16* Vbase = Vt + (size_t)(kv * 256) * 4096 + b * 2048;

  int kfix[4], vfix[4];
#pragma unroll
  for (int jj = 0; jj < 4; jj++) {
    int ci = jj * 256 + tid;
    int krow = ci >> 5, kc = ci & 31;
    int kcg = (kc & 24) | ((kc ^ krow) & 7);
    kfix[jj] = krow * QKVS + kcg * 8;
    int vrow = ci >> 2, vc = ci & 3;
    int vg = (vc - (vrow >> 1)) & 3;
    vfix[jj] = vrow * 4096 + vg * 8;
  }
  int koff = 0, voff = 0;

  auto STAGE = [&](u16* Kd, u16* Vd) {
#pragma unroll
    for (int jj = 0; jj < 4; jj++)
      gload16(Kbase + kfix[jj] + koff, (char*)Kd + (jj * 256 + tid) * 16);
#pragma unroll
    for (int jj = 0; jj < 4; jj++)
      gload16(Vbase + vfix[jj] + voff, (char*)Vd + (jj * 256 + tid) * 16);
    koff += 32 * QKVS;
    voff += 32;
  };

  auto COMPUTE = [&](int t, const u16* Kc, const u16* Vc) {
    f32x16 s;
#pragma unroll
    for (int jj = 0; jj < 16; jj++) s[jj] = 0.f;
#pragma unroll
    for (int kc = 0; kc < 16; kc++) {
      int ch = kc * 2 + hi;
      int cs = (ch & 24) | ((ch ^ r31) & 7);
      bf16x8 kf = *(const bf16x8*)((const char*)Kc + r31 * 512 + cs * 16);
      s = MFMA32(kf, qreg[kc], s);
    }

    const float C = 0.0625f * LOG2E;
    float z[16];
#pragma unroll
    for (int jj = 0; jj < 16; jj++) z[jj] = s[jj] * C;
    if (t == tlim) {
#pragma unroll
      for (int jj = 0; jj < 16; jj++) {
        int kvg = t * 32 + (jj & 3) + 8 * (jj >> 2) + 4 * hi;
        if (kvg > qloc) z[jj] = -1e30f;
      }
    }

    float m0 = z[0];
#pragma unroll
    for (int jj = 1; jj < 16; jj++) m0 = fmaxf(m0, z[jj]);
    m0 = fmaxf(m0, __shfl_xor(m0, 32));
    if (__any(m0 > mrow + 11.54f)) {  // rare after first tile
      float mn = fmaxf(mrow, m0);
      float alpha = exp2f(mrow - mn);
      mrow = mn;
      lrow *= alpha;
#pragma unroll
      for (int jj = 0; jj < 16; jj++) {
        float a = __shfl(alpha, (jj & 3) + 8 * (jj >> 2) + 4 * hi);
#pragma unroll
        for (int df = 0; df < 8; df++) o[df][jj] *= a;
      }
    }
    float sum = 0.f;
#pragma unroll
    for (int jj = 0; jj < 16; jj++) {
      z[jj] = exp2f(z[jj] - mrow);
      sum += z[jj];
    }
    sum += __shfl_xor(sum, 32);
    lrow += sum;

    unsigned a0 = cvtpk(z[0], z[1]), a2 = cvtpk(z[4], z[5]);
    swap32(a0, a2);
    unsigned a1 = cvtpk(z[2], z[3]), a3 = cvtpk(z[6], z[7]);
    swap32(a1, a3);
    unsigned b0 = cvtpk(z[8], z[9]), b2 = cvtpk(z[12], z[13]);
    swap32(b0, b2);
    unsigned b1 = cvtpk(z[10], z[11]), b3 = cvtpk(z[14], z[15]);
    swap32(b1, b3);
    union UU { unsigned u[4]; bf16x8 v; };
    UU ua; ua.u[0] = a0; ua.u[1] = a1; ua.u[2] = a2; ua.u[3] = a3;
    UU ub; ub.u[0] = b0; ub.u[1] = b1; ub.u[2] = b2; ub.u[3] = b3;
    bf16x8 pa0 = ua.v, pa1 = ub.v;

#pragma unroll
    for (int df = 0; df < 8; df++) {
      int vr = df * 32 + r31;
      int c0 = (hi + (vr >> 1)) & 3;
      int c1 = (2 + hi + (vr >> 1)) & 3;
      bf16x8 v0 = *(const bf16x8*)((const char*)Vc + vr * 64 + c0 * 16);
      bf16x8 v1 = *(const bf16x8*)((const char*)Vc + vr * 64 + c1 * 16);
      o[df] = MFMA32(pa0, v0, o[df]);
      o[df] = MFMA32(pa1, v1, o[df]);
    }
  };

  STAGE(aK0, aV0);
  __syncthreads();

  for (int t = 0; t < nt; t += 2) {
    STAGE(aK1, aV1);
    if (t <= tlim) COMPUTE(t, aK0, aV0);
    __syncthreads();
    if (t + 2 < nt) STAGE(aK0, aV0);
    if (t + 1 <= tlim) COMPUTE(t + 1, aK1, aV1);
    __syncthreads();
  }

  float rl = 1.f / lrow;
  size_t rowbase = (size_t)(b * 2048 + qb * 128 + w * 32);
#pragma unroll
  for (int jj = 0; jj < 16; jj++) {
    float rr2 = __shfl(rl, (jj & 3) + 8 * (jj >> 2) + 4 * hi);
    int qr = (jj & 3) + 8 * (jj >> 2) + 4 * hi;
#pragma unroll
    for (int df = 0; df < 8; df++)
      AO[(rowbase + qr) * 4096 + h * 256 + df * 32 + r31] = f2bf(o[df][jj] * rr2);
  }
}

// ---------------- host ----------------

// ws layout (bytes), high-water 113.2 MB:
// Xb @0 (16MB, dead after QKV gemm) -- AO @0 (32MB) aliases it + Wqkvt head.
// Wqkvt @16.7M (24MB), dead after gemm. Vt @33.5M (8MB) aliases Wqkvt tail.
// Wot @41.9M (16MB, persists). QKV @58.7M (48MB). TAB @109.1M (4MB).
#define OFF_AO    0u
#define OFF_XB    0u
#define OFF_WQKVT 16777216u
#define OFF_VT    33554432u
#define OFF_WOT   41943040u
#define OFF_QKV   58720256u
#define OFF_TAB   109051904u

extern "C" void kernel_launch(void* const* d_in, const int* in_sizes, int n_in,
                              void* d_out, int out_size, void* d_ws, size_t ws_size,
                              hipStream_t stream) {
  const float* hs = (const float*)d_in[0];
  const int* pos = (const int*)d_in[1];
  const float* wq = (const float*)d_in[2];
  const float* wk = (const float*)d_in[3];
  const float* wv = (const float*)d_in[4];
  const float* wo = (const float*)d_in[5];
  float* out = (float*)d_out;
  char* ws = (char*)d_ws;

  u16* Xb    = (u16*)(ws + OFF_XB);
  u16* Wqkvt = (u16*)(ws + OFF_WQKVT);
  u16* Vt    = (u16*)(ws + OFF_VT);
  u16* Wot   = (u16*)(ws + OFF_WOT);
  u16* QKV   = (u16*)(ws + OFF_QKV);
  float2* Tab = (float2*)(ws + OFF_TAB);
  u16* AO    = (u16*)(ws + OFF_AO);

  dim3 tb(32, 8);

  // rope cos/sin table (only place with device trig; consumed by gemm256 epilogue)
  k_ropetab<<<2048, 256, 0, stream>>>(pos, Tab);

  // prep: convert + all weight transposes (one launch)
  k_convert_f32_bf16<<<8192, 256, 0, stream>>>(hs, Xb, 2097152);
  k_transpose_all<<<20480, 256, 0, stream>>>(wq, wk, wv, wo, Wqkvt, Wot);

  // fused QKV projection + RoPE epilogue (Q/K heads rope'd in epilogue)
  (void)hipFuncSetAttribute((const void*)k_gemm256,
                            hipFuncAttributeMaxDynamicSharedMemorySize, 131072);
  k_gemm256<<<dim3(24, 16), 512, 131072, stream>>>(Xb, Wqkvt, QKV, 6144, 2048, Tab);

  // V^T (V = cols 5120..6143) -> Vt [1024][4096]
  k_transpose_bf16<<<dim3(32, 128), tb, 0, stream>>>(QKV + 5120, Vt, 4096, QKVS);

  // flash attention (r10 kernel: no table, XCD-pinned, L2-resident K/V)
  k_attn<<<dim3(512), 256, 0, stream>>>(QKV, Vt, AO);

  // output projection (fp32 out), m97 structure
  k_gemm_bt<0><<<dim3(16, 32), 256, 0, stream>>>(AO, Wot, out, 4096, 2048, 4096);
}

// Round 19
// 453.842 us; speedup vs baseline: 1.2188x; 1.0288x over previous
//
#include <hip/hip_runtime.h>

typedef unsigned short u16;
typedef __bf16 bf16_t;
typedef bf16_t bf16x8 __attribute__((ext_vector_type(8)));
typedef float f32x4 __attribute__((ext_vector_type(4)));
typedef float f32x16 __attribute__((ext_vector_type(16)));

#define LOG2E 1.4426950408889634f
#define QKVS 6144  // row stride of fused QKV activation buffer

__device__ __forceinline__ u16 f2bf(float f) {
  union { float f; unsigned u; } c; c.f = f;
  unsigned r = c.u + 0x7fffu + ((c.u >> 16) & 1u);
  return (u16)(r >> 16);
}
__device__ __forceinline__ float bf2f(u16 u) {
  union { unsigned u; float f; } c; c.u = ((unsigned)u) << 16;
  return c.f;
}

__device__ __forceinline__ void gload16(const void* g, void* l) {
  __builtin_amdgcn_global_load_lds(
      (const __attribute__((address_space(1))) unsigned int*)g,
      (__attribute__((address_space(3))) unsigned int*)l, 16, 0, 0);
}

__device__ __forceinline__ unsigned cvtpk(float lo, float hi) {
  unsigned r;
  asm("v_cvt_pk_bf16_f32 %0, %1, %2" : "=v"(r) : "v"(lo), "v"(hi));
  return r;
}
__device__ __forceinline__ void swap32(unsigned& a, unsigned& b) {
  asm("v_permlane32_swap_b32 %0, %1" : "+v"(a), "+v"(b));
}

#define MFMA16(a, b, c) __builtin_amdgcn_mfma_f32_16x16x32_bf16((a), (b), (c), 0, 0, 0)
#define MFMA32(a, b, c) __builtin_amdgcn_mfma_f32_32x32x16_bf16((a), (b), (c), 0, 0, 0)

// ---------------- unified prep kernel ----------------
// [0,8192): convert hs f32->bf16 | [8192,16384): wq^T | [16384,18432): wk^T |
// [18432,20480): wv^T | [20480,28672): wo^T | [28672,30720): rope table.
// Branch is block-uniform, so barrier usage stays legal.
__global__ __launch_bounds__(256) void k_prep(const float* __restrict__ hs,
                                              const int* __restrict__ pos,
                                              const float* __restrict__ wq,
                                              const float* __restrict__ wk,
                                              const float* __restrict__ wv,
                                              const float* __restrict__ wo,
                                              u16* __restrict__ Xb,
                                              u16* __restrict__ Wqkvt,
                                              u16* __restrict__ Wot,
                                              float2* __restrict__ tab) {
  __shared__ float tile[32][33];
  const int fb = blockIdx.x;
  if (fb < 8192) {  // convert
    int i = fb * 256 + threadIdx.x;
    float4 v = ((const float4*)hs)[i];
    ushort4 o;
    o.x = f2bf(v.x); o.y = f2bf(v.y); o.z = f2bf(v.z); o.w = f2bf(v.w);
    ((ushort4*)Xb)[i] = o;
    return;
  }
  if (fb >= 28672) {  // rope table (only device trig in the pipeline)
    int idx = (fb - 28672) * 256 + threadIdx.x;
    int i = idx & 127, row = idx >> 7;
    float p = (float)pos[row];
    float f = p * exp2f((float)i * (-13.287712379549449f / 128.f));
    float sn, cs;
    sincosf(f, &sn, &cs);
    tab[idx] = make_float2(cs, sn);
    return;
  }
  // weight transposes: out[C][R] = bf16(in[R][C])
  const float* in;
  u16* out;
  int R, C, bxi, byi;
  if (fb < 16384) {
    in = wq; out = Wqkvt; R = 2048; C = 4096;
    int l = fb - 8192; bxi = l & 127; byi = l >> 7;
  } else if (fb < 18432) {
    in = wk; out = Wqkvt + 4096 * 2048; R = 2048; C = 1024;
    int l = fb - 16384; bxi = l & 31; byi = l >> 5;
  } else if (fb < 20480) {
    in = wv; out = Wqkvt + 5120 * 2048; R = 2048; C = 1024;
    int l = fb - 18432; bxi = l & 31; byi = l >> 5;
  } else {
    in = wo; out = Wot; R = 4096; C = 2048;
    int l = fb - 20480; bxi = l & 63; byi = l >> 6;
  }
  int tx = threadIdx.x & 31, ty = threadIdx.x >> 5;
  int bx = bxi * 32, by = byi * 32;
#pragma unroll
  for (int i = 0; i < 4; i++)
    tile[ty + i * 8][tx] = in[(size_t)(by + ty + i * 8) * C + bx + tx];
  __syncthreads();
#pragma unroll
  for (int i = 0; i < 4; i++)
    out[(size_t)(bx + ty + i * 8) * R + by + tx] = f2bf(tile[tx][ty + i * 8]);
}

// ---------------- GEMM m97-style (kept for out-proj) ----------------

template <int OUT_BF16>
__global__ __launch_bounds__(256) void k_gemm_bt(const u16* __restrict__ A,
                                                 const u16* __restrict__ Bt,
                                                 void* __restrict__ C, int M, int N, int K) {
  __shared__ u16 As[128 * 64];
  __shared__ u16 Bs[128 * 64];
  const int tid = threadIdx.x;
  const int lane = tid & 63;
  const int w = tid >> 6;
  const int l15 = lane & 15, l4 = lane >> 4;
  const int wr = w >> 1, wc = w & 1;
  const int bx = blockIdx.x, by = blockIdx.y;

  f32x4 acc[4][4];
#pragma unroll
  for (int a = 0; a < 4; a++)
#pragma unroll
    for (int b2 = 0; b2 < 4; b2++) acc[a][b2] = (f32x4){0.f, 0.f, 0.f, 0.f};

  const u16* Abase = A + (size_t)by * 128 * K;
  const u16* Bbase = Bt + (size_t)bx * 128 * K;

  for (int kk = 0; kk < K; kk += 64) {
    __syncthreads();
#pragma unroll
    for (int j = 0; j < 4; j++) {
      int ci = w * 256 + j * 64 + lane;
      int row = ci >> 3, c = ci & 7;
      gload16(Abase + (size_t)row * K + kk + c * 8, (char*)As + ci * 16);
      gload16(Bbase + (size_t)row * K + kk + c * 8, (char*)Bs + ci * 16);
    }
    __syncthreads();
#pragma unroll
    for (int kc = 0; kc < 2; kc++) {
      int kb = kc * 64 + l4 * 16;
      bf16x8 av[4], bv[4];
#pragma unroll
      for (int mt = 0; mt < 4; mt++)
        av[mt] = *(const bf16x8*)((const char*)As + (wr * 64 + mt * 16 + l15) * 128 + kb);
#pragma unroll
      for (int nt = 0; nt < 4; nt++)
        bv[nt] = *(const bf16x8*)((const char*)Bs + (wc * 64 + nt * 16 + l15) * 128 + kb);
#pragma unroll
      for (int mt = 0; mt < 4; mt++)
#pragma unroll
        for (int nt = 0; nt < 4; nt++) acc[mt][nt] = MFMA16(av[mt], bv[nt], acc[mt][nt]);
    }
  }
#pragma unroll
  for (int mt = 0; mt < 4; mt++) {
#pragma unroll
    for (int nt = 0; nt < 4; nt++) {
      int col = bx * 128 + wc * 64 + nt * 16 + l15;
#pragma unroll
      for (int r = 0; r < 4; r++) {
        int row = by * 128 + wr * 64 + mt * 16 + l4 * 4 + r;
        if (OUT_BF16)
          ((u16*)C)[(size_t)row * N + col] = f2bf(acc[mt][nt][r]);
        else
          ((float*)C)[(size_t)row * N + col] = acc[mt][nt][r];
      }
    }
  }
}

// ---------------- GEMM 256x256 8-phase + fused RoPE / V-transpose epilogues ----------------
// Main loop identical to r10 (race-safe). bx<20 (Q/K heads): rope epilogue with
// conflict-free float4 exchange (r18). bx>=20 (V heads): transpose epilogue --
// pack acc into LDS [256 col][136 row] bf16 (b64 writes), read b128 rows of 8
// consecutive tokens, coalesced 16B stores into Vt[1024][4096]. Replaces the
// separate V^T transpose pass.

__global__ __launch_bounds__(512, 1) void k_gemm256(const u16* __restrict__ A,
                                                    const u16* __restrict__ Bt,
                                                    u16* __restrict__ C, int N, int K,
                                                    const float2* __restrict__ tab,
                                                    u16* __restrict__ Vt) {
  extern __shared__ char smem[];
  const int tid = threadIdx.x;
  const int lane = tid & 63, w = tid >> 6;
  const int l15 = lane & 15, l4 = lane >> 4;
  const int wr = w >> 2, wc = w & 3;
  const int bx = blockIdx.x, by = blockIdx.y;
  const int NT = K >> 6;

  const u16* Ab = A + (size_t)(by * 256) * K;
  const u16* Bb = Bt + (size_t)(bx * 256) * K;

  int srcoff[2], dstoff[2];
#pragma unroll
  for (int rr = 0; rr < 2; rr++) {
    int ci = rr * 512 + tid;
    int lc = ci ^ (((ci >> 5) & 1) << 1);
    int kc = lc >> 9, row = (lc >> 2) & 127, g2 = lc & 3;
    srcoff[rr] = row * K + kc * 32 + g2 * 8;
    dstoff[rr] = ci * 16;
  }

  auto SH = [&](int Tg, int halfidx) {
    const u16* base = (halfidx < 2) ? (Ab + (size_t)(halfidx * 128) * K)
                                    : (Bb + (size_t)((halfidx - 2) * 128) * K);
    char* dst = smem + (Tg & 1) * 65536 + halfidx * 16384;
    int kk = Tg * 64;
#pragma unroll
    for (int rr = 0; rr < 2; rr++)
      gload16(base + srcoff[rr] + kk, dst + dstoff[rr]);
  };

  auto lda = [&](int c, int kc, int mrow4) -> bf16x8 {
    int L = kc * 8192 + (mrow4 * 16 + l15) * 64 + l4 * 16;
    int P = L ^ (((L >> 9) & 1) << 5);
    return *(const bf16x8*)(smem + c * 65536 + wr * 16384 + P);
  };
  auto ldb = [&](int c, int kc, int j) -> bf16x8 {
    int L = kc * 8192 + ((wc & 1) * 64 + j * 16 + l15) * 64 + l4 * 16;
    int P = L ^ (((L >> 9) & 1) << 5);
    return *(const bf16x8*)(smem + c * 65536 + 32768 + (wc >> 1) * 16384 + P);
  };

  f32x4 acc[8][4];
#pragma unroll
  for (int i = 0; i < 8; i++)
#pragma unroll
    for (int j = 0; j < 4; j++) acc[i][j] = (f32x4){0.f, 0.f, 0.f, 0.f};

  SH(0, 0); SH(0, 1); SH(0, 2); SH(0, 3);
  SH(1, 2); SH(1, 3);
  asm volatile("s_waitcnt vmcnt(4)" ::: "memory");
  __builtin_amdgcn_s_barrier();
  asm volatile("" ::: "memory");

  bf16x8 bv[2][4];
  for (int T = 0; T < NT; ++T) {
    const int c = T & 1;
#pragma unroll
    for (int q = 0; q < 4; q++) {
      const int kc = q & 1, mh = q >> 1;
      bf16x8 av[4];
      if (q < 2) {
#pragma unroll
        for (int j = 0; j < 4; j++) bv[kc][j] = ldb(c, kc, j);
      }
#pragma unroll
      for (int ii = 0; ii < 4; ii++) av[ii] = lda(c, kc, mh * 4 + ii);
      if (q == 0)      { if (T + 1 < NT) SH(T + 1, 0); }
      else if (q == 1) { if (T + 1 < NT) SH(T + 1, 1); }
      else if (q == 2) { if (T + 2 < NT) SH(T + 2, 2); }
      else             { if (T + 2 < NT) SH(T + 2, 3); }
      if (q == 3) {
        if (T < NT - 2)       asm volatile("s_waitcnt vmcnt(4)" ::: "memory");
        else if (T == NT - 2) asm volatile("s_waitcnt vmcnt(0)" ::: "memory");
      }
      asm volatile("" ::: "memory");
      __builtin_amdgcn_s_barrier();
      asm volatile("" ::: "memory");
      asm volatile("s_waitcnt lgkmcnt(0)" ::: "memory");
      __builtin_amdgcn_sched_barrier(0);
      __builtin_amdgcn_s_setprio(1);
#pragma unroll
      for (int ii = 0; ii < 4; ii++)
#pragma unroll
        for (int j = 0; j < 4; j++)
          acc[mh * 4 + ii][j] = MFMA16(av[ii], bv[kc][j], acc[mh * 4 + ii][j]);
      __builtin_amdgcn_s_setprio(0);
      asm volatile("" ::: "memory");
      __builtin_amdgcn_s_barrier();
      asm volatile("" ::: "memory");
    }
  }

  if (bx < 20) {
    // ---- fused RoPE epilogue (Q + K heads), conflict-free float4 exchange ----
    float4* X4 = (float4*)smem;
    const float sgn = (wc < 2) ? -1.f : 1.f;
    const int ptid = tid ^ 128;  // partner wave: wc ^= 2, same wr/lane
#pragma unroll
    for (int ih = 0; ih < 2; ih++) {
      __syncthreads();
#pragma unroll
      for (int i2 = 0; i2 < 4; i2++)
#pragma unroll
        for (int j2 = 0; j2 < 4; j2++) {
          f32x4 a = acc[ih * 4 + i2][j2];
          X4[(i2 * 4 + j2) * 512 + tid] = make_float4(a[0], a[1], a[2], a[3]);
        }
      __syncthreads();
#pragma unroll
      for (int i2 = 0; i2 < 4; i2++) {
#pragma unroll
        for (int j2 = 0; j2 < 4; j2++) {
          int col = bx * 256 + wc * 64 + j2 * 16 + l15;
          int ti = (wc & 1) * 64 + j2 * 16 + l15;  // freq index (same both halves)
          float4 part = X4[(i2 * 4 + j2) * 512 + ptid];
          float pa[4] = {part.x, part.y, part.z, part.w};
#pragma unroll
          for (int r2 = 0; r2 < 4; r2++) {
            int row = by * 256 + wr * 128 + (ih * 4 + i2) * 16 + l4 * 4 + r2;
            float mine = acc[ih * 4 + i2][j2][r2];
            float2 t = tab[(size_t)row * 128 + ti];
            C[(size_t)row * N + col] = f2bf(mine * t.x + sgn * pa[r2] * t.y);
          }
        }
      }
    }
  } else {
    // ---- fused V-transpose epilogue: write Vt[vc][token] directly ----
    // LDS tile lt[256 col][136 row] u16 (136 -> 272B col stride, 16B-aligned).
    // lrow = wr*64 + i2*16 + l4*4 + r2 maps to token runs {ih*64, 128+ih*64}.
    u16* lt = (u16*)smem;
    const int vbase = bx * 256 - 5120;
#pragma unroll
    for (int ih = 0; ih < 2; ih++) {
      __syncthreads();
#pragma unroll
      for (int i2 = 0; i2 < 4; i2++) {
#pragma unroll
        for (int j2 = 0; j2 < 4; j2++) {
          int col = wc * 64 + j2 * 16 + l15;
          int lrow = wr * 64 + i2 * 16 + l4 * 4;
          f32x4 a = acc[ih * 4 + i2][j2];
          ushort4 pk;
          pk.x = f2bf(a[0]); pk.y = f2bf(a[1]); pk.z = f2bf(a[2]); pk.w = f2bf(a[3]);
          *(ushort4*)&lt[col * 136 + lrow] = pk;  // 8B, aligned (272*col + 8*k)
        }
      }
      __syncthreads();
#pragma unroll
      for (int v = 0; v < 8; v++) {
        int idx2 = v * 512 + tid;
        int vc = idx2 >> 4, tv = idx2 & 15;
        bf16x8 val = *(const bf16x8*)&lt[vc * 136 + tv * 8];
        int token = by * 256 + ((tv < 8) ? (ih * 64 + tv * 8) : (128 + ih * 64 + (tv - 8) * 8));
        *(bf16x8*)&Vt[(size_t)(vbase + vc) * 4096 + token] = val;
      }
    }
  }
}

// ---------------- flash attention (byte-identical to r10/r16/r18's 226 us kernel) ----------------

__shared__ __align__(16) u16 aK0[8192];
__shared__ __align__(16) u16 aK1[8192];
__shared__ __align__(16) u16 aV0[8192];
__shared__ __align__(16) u16 aV1[8192];

__global__ __launch_bounds__(256, 2) void k_attn(const u16* __restrict__ QKV,
                                                 const u16* __restrict__ Vt,
                                                 u16* __restrict__ AO) {
  const int tid = threadIdx.x, lane = tid & 63, w = tid >> 6;
  const int r31 = lane & 31, hi = lane >> 5;

  const int flat = blockIdx.x;
  const int r = flat & 7;            // XCD (round-robin dispatch)
  const int idx = flat >> 3;
  const int b = r >> 2, kv = r & 3;  // one (b,kv) per XCD: 2 MB K/V, L2-resident
  const int half = idx >> 5, j = idx & 31;
  const int qb = half ? 15 - (j >> 1) : (j >> 1);
  const int h = kv * 4 + (j & 1) + 2 * half;

  bf16x8 qreg[16];
  {
    const u16* qp = QKV + (size_t)(b * 2048 + qb * 128 + w * 32 + r31) * QKVS + h * 256 + hi * 8;
#pragma unroll
    for (int kc = 0; kc < 16; kc++) qreg[kc] = *(const bf16x8*)(qp + kc * 16);
  }

  f32x16 o[8];
#pragma unroll
  for (int df = 0; df < 8; df++)
#pragma unroll
    for (int jj = 0; jj < 16; jj++) o[df][jj] = 0.f;
  float mrow = -3e38f, lrow = 0.f;

  const int nt = 4 * qb + 4;  // always even
  const int tlim = 4 * qb + w;
  const int qloc = qb * 128 + w * 32 + r31;
  const u16* Kbase = QKV + (size_t)(b * 2048) * QKVS + 4096 + kv * 256;
  const u16* Vbase = Vt + (size_t)(kv * 256) * 4096 + b * 2048;

  int kfix[4], vfix[4];
#pragma unroll
  for (int jj = 0; jj < 4; jj++) {
    int ci = jj * 256 + tid;
    int krow = ci >> 5, kc = ci & 31;
    int kcg = (kc & 24) | ((kc ^ krow) & 7);
    kfix[jj] = krow * QKVS + kcg * 8;
    int vrow = ci >> 2, vc = ci & 3;
    int vg = (vc - (vrow >> 1)) & 3;
    vfix[jj] = vrow * 4096 + vg * 8;
  }
  int koff = 0, voff = 0;

  auto STAGE = [&](u16* Kd, u16* Vd) {
#pragma unroll
    for (int jj = 0; jj < 4; jj++)
      gload16(Kbase + kfix[jj] + koff, (char*)Kd + (jj * 256 + tid) * 16);
#pragma unroll
    for (int jj = 0; jj < 4; jj++)
      gload16(Vbase + vfix[jj] + voff, (char*)Vd + (jj * 256 + tid) * 16);
    koff += 32 * QKVS;
    voff += 32;
  };

  auto COMPUTE = [&](int t, const u16* Kc, const u16* Vc) {
    f32x16 s;
#pragma unroll
    for (int jj = 0; jj < 16; jj++) s[jj] = 0.f;
#pragma unroll
    for (int kc = 0; kc < 16; kc++) {
      int ch = kc * 2 + hi;
      int cs = (ch & 24) | ((ch ^ r31) & 7);
      bf16x8 kf = *(const bf16x8*)((const char*)Kc + r31 * 512 + cs * 16);
      s = MFMA32(kf, qreg[kc], s);
    }

    const float C = 0.0625f * LOG2E;
    float z[16];
#pragma unroll
    for (int jj = 0; jj < 16; jj++) z[jj] = s[jj] * C;
    if (t == tlim) {
#pragma unroll
      for (int jj = 0; jj < 16; jj++) {
        int kvg = t * 32 + (jj & 3) + 8 * (jj >> 2) + 4 * hi;
        if (kvg > qloc) z[jj] = -1e30f;
      }
    }

    float m0 = z[0];
#pragma unroll
    for (int jj = 1; jj < 16; jj++) m0 = fmaxf(m0, z[jj]);
    m0 = fmaxf(m0, __shfl_xor(m0, 32));
    if (__any(m0 > mrow + 11.54f)) {  // rare after first tile
      float mn = fmaxf(mrow, m0);
      float alpha = exp2f(mrow - mn);
      mrow = mn;
      lrow *= alpha;
#pragma unroll
      for (int jj = 0; jj < 16; jj++) {
        float a = __shfl(alpha, (jj & 3) + 8 * (jj >> 2) + 4 * hi);
#pragma unroll
        for (int df = 0; df < 8; df++) o[df][jj] *= a;
      }
    }
    float sum = 0.f;
#pragma unroll
    for (int jj = 0; jj < 16; jj++) {
      z[jj] = exp2f(z[jj] - mrow);
      sum += z[jj];
    }
    sum += __shfl_xor(sum, 32);
    lrow += sum;

    unsigned a0 = cvtpk(z[0], z[1]), a2 = cvtpk(z[4], z[5]);
    swap32(a0, a2);
    unsigned a1 = cvtpk(z[2], z[3]), a3 = cvtpk(z[6], z[7]);
    swap32(a1, a3);
    unsigned b0 = cvtpk(z[8], z[9]), b2 = cvtpk(z[12], z[13]);
    swap32(b0, b2);
    unsigned b1 = cvtpk(z[10], z[11]), b3 = cvtpk(z[14], z[15]);
    swap32(b1, b3);
    union UU { unsigned u[4]; bf16x8 v; };
    UU ua; ua.u[0] = a0; ua.u[1] = a1; ua.u[2] = a2; ua.u[3] = a3;
    UU ub; ub.u[0] = b0; ub.u[1] = b1; ub.u[2] = b2; ub.u[3] = b3;
    bf16x8 pa0 = ua.v, pa1 = ub.v;

#pragma unroll
    for (int df = 0; df < 8; df++) {
      int vr = df * 32 + r31;
      int c0 = (hi + (vr >> 1)) & 3;
      int c1 = (2 + hi + (vr >> 1)) & 3;
      bf16x8 v0 = *(const bf16x8*)((const char*)Vc + vr * 64 + c0 * 16);
      bf16x8 v1 = *(const bf16x8*)((const char*)Vc + vr * 64 + c1 * 16);
      o[df] = MFMA32(pa0, v0, o[df]);
      o[df] = MFMA32(pa1, v1, o[df]);
    }
  };

  STAGE(aK0, aV0);
  __syncthreads();

  for (int t = 0; t < nt; t += 2) {
    STAGE(aK1, aV1);
    if (t <= tlim) COMPUTE(t, aK0, aV0);
    __syncthreads();
    if (t + 2 < nt) STAGE(aK0, aV0);
    if (t + 1 <= tlim) COMPUTE(t + 1, aK1, aV1);
    __syncthreads();
  }

  float rl = 1.f / lrow;
  size_t rowbase = (size_t)(b * 2048 + qb * 128 + w * 32);
#pragma unroll
  for (int jj = 0; jj < 16; jj++) {
    float rr2 = __shfl(rl, (jj & 3) + 8 * (jj >> 2) + 4 * hi);
    int qr = (jj & 3) + 8 * (jj >> 2) + 4 * hi;
#pragma unroll
    for (int df = 0; df < 8; df++)
      AO[(rowbase + qr) * 4096 + h * 256 + df * 32 + r31] = f2bf(o[df][jj] * rr2);
  }
}

// ---------------- host ----------------

// ws layout (bytes), high-water 113.2 MB:
// Xb @0 (16MB, dead after QKV gemm) -- AO @0 (32MB) aliases it + Wqkvt head.
// Wqkvt @16.7M (24MB), dead after gemm. Vt @33.5M (8MB) aliases Wqkvt tail
// (written by gemm256 epilogue, after those weight rows are consumed... NOTE:
// Vt region = Wqkvt rows 4194304.. ; gemm256 writes Vt DURING the gemm --
// but only in the epilogue, after ALL K-tiles of that block are consumed.
// Cross-block hazard: block (bx>=20, by) writes Vt while another block may
// still be reading Wqkvt rows that alias it. Vt @33.5M aliases Wqkvt rows
// 8.4M..16.8M bytes = rows 2048..4095 of Wqkvt (Q-head weights), which ARE
// still being read by in-flight Q blocks. -> moved Vt to its own region
// @113.2M to avoid any overlap (high-water 121.6 MB).
#define OFF_AO    0u
#define OFF_XB    0u
#define OFF_WQKVT 16777216u
#define OFF_WOT   41943040u
#define OFF_QKV   58720256u
#define OFF_TAB   109051904u
#define OFF_VT    113246208u

extern "C" void kernel_launch(void* const* d_in, const int* in_sizes, int n_in,
                              void* d_out, int out_size, void* d_ws, size_t ws_size,
                              hipStream_t stream) {
  const float* hs = (const float*)d_in[0];
  const int* pos = (const int*)d_in[1];
  const float* wq = (const float*)d_in[2];
  const float* wk = (const float*)d_in[3];
  const float* wv = (const float*)d_in[4];
  const float* wo = (const float*)d_in[5];
  float* out = (float*)d_out;
  char* ws = (char*)d_ws;

  u16* Xb    = (u16*)(ws + OFF_XB);
  u16* Wqkvt = (u16*)(ws + OFF_WQKVT);
  u16* Wot   = (u16*)(ws + OFF_WOT);
  u16* QKV   = (u16*)(ws + OFF_QKV);
  float2* Tab = (float2*)(ws + OFF_TAB);
  u16* Vt    = (u16*)(ws + OFF_VT);
  u16* AO    = (u16*)(ws + OFF_AO);

  // unified prep: convert + all weight transposes + rope table (one launch)
  k_prep<<<30720, 256, 0, stream>>>(hs, pos, wq, wk, wv, wo, Xb, Wqkvt, Wot, Tab);

  // fused QKV projection + RoPE epilogue (Q/K) + V-transpose epilogue (V)
  (void)hipFuncSetAttribute((const void*)k_gemm256,
                            hipFuncAttributeMaxDynamicSharedMemorySize, 131072);
  k_gemm256<<<dim3(24, 16), 512, 131072, stream>>>(Xb, Wqkvt, QKV, 6144, 2048, Tab, Vt);

  // flash attention (r10 kernel: no table, XCD-pinned, L2-resident K/V)
  k_attn<<<dim3(512), 256, 0, stream>>>(QKV, Vt, AO);

  // output projection (fp32 out), m97 structure
  k_gemm_bt<0><<<dim3(16, 32), 256, 0, stream>>>(AO, Wot, out, 4096, 2048, 4096);
}

// Round 20
// 442.956 us; speedup vs baseline: 1.2488x; 1.0246x over previous
//
#include <hip/hip_runtime.h>

typedef unsigned short u16;
typedef __bf16 bf16_t;
typedef bf16_t bf16x8 __attribute__((ext_vector_type(8)));
typedef float f32x4 __attribute__((ext_vector_type(4)));
typedef float f32x16 __attribute__((ext_vector_type(16)));

#define LOG2E 1.4426950408889634f
#define QKVS 6144  // row stride of fused QKV activation buffer

__device__ __forceinline__ u16 f2bf(float f) {
  union { float f; unsigned u; } c; c.f = f;
  unsigned r = c.u + 0x7fffu + ((c.u >> 16) & 1u);
  return (u16)(r >> 16);
}
__device__ __forceinline__ float bf2f(u16 u) {
  union { unsigned u; float f; } c; c.u = ((unsigned)u) << 16;
  return c.f;
}

__device__ __forceinline__ void gload16(const void* g, void* l) {
  __builtin_amdgcn_global_load_lds(
      (const __attribute__((address_space(1))) unsigned int*)g,
      (__attribute__((address_space(3))) unsigned int*)l, 16, 0, 0);
}

__device__ __forceinline__ unsigned cvtpk(float lo, float hi) {
  unsigned r;
  asm("v_cvt_pk_bf16_f32 %0, %1, %2" : "=v"(r) : "v"(lo), "v"(hi));
  return r;
}
__device__ __forceinline__ void swap32(unsigned& a, unsigned& b) {
  asm("v_permlane32_swap_b32 %0, %1" : "+v"(a), "+v"(b));
}

#define MFMA16(a, b, c) __builtin_amdgcn_mfma_f32_16x16x32_bf16((a), (b), (c), 0, 0, 0)
#define MFMA32(a, b, c) __builtin_amdgcn_mfma_f32_32x32x16_bf16((a), (b), (c), 0, 0, 0)

// ---------------- unified prep kernel ----------------
// [0,8192): convert hs f32->bf16 | [8192,16384): wq^T | [16384,18432): wk^T |
// [18432,20480): wv^T | [20480,28672): wo^T | [28672,30720): rope table.
__global__ __launch_bounds__(256) void k_prep(const float* __restrict__ hs,
                                              const int* __restrict__ pos,
                                              const float* __restrict__ wq,
                                              const float* __restrict__ wk,
                                              const float* __restrict__ wv,
                                              const float* __restrict__ wo,
                                              u16* __restrict__ Xb,
                                              u16* __restrict__ Wqkvt,
                                              u16* __restrict__ Wot,
                                              float2* __restrict__ tab) {
  __shared__ float tile[32][33];
  const int fb = blockIdx.x;
  if (fb < 8192) {  // convert
    int i = fb * 256 + threadIdx.x;
    float4 v = ((const float4*)hs)[i];
    ushort4 o;
    o.x = f2bf(v.x); o.y = f2bf(v.y); o.z = f2bf(v.z); o.w = f2bf(v.w);
    ((ushort4*)Xb)[i] = o;
    return;
  }
  if (fb >= 28672) {  // rope table (only device trig in the pipeline)
    int idx = (fb - 28672) * 256 + threadIdx.x;
    int i = idx & 127, row = idx >> 7;
    float p = (float)pos[row];
    float f = p * exp2f((float)i * (-13.287712379549449f / 128.f));
    float sn, cs;
    sincosf(f, &sn, &cs);
    tab[idx] = make_float2(cs, sn);
    return;
  }
  const float* in;
  u16* out;
  int R, C, bxi, byi;
  if (fb < 16384) {
    in = wq; out = Wqkvt; R = 2048; C = 4096;
    int l = fb - 8192; bxi = l & 127; byi = l >> 7;
  } else if (fb < 18432) {
    in = wk; out = Wqkvt + 4096 * 2048; R = 2048; C = 1024;
    int l = fb - 16384; bxi = l & 31; byi = l >> 5;
  } else if (fb < 20480) {
    in = wv; out = Wqkvt + 5120 * 2048; R = 2048; C = 1024;
    int l = fb - 18432; bxi = l & 31; byi = l >> 5;
  } else {
    in = wo; out = Wot; R = 4096; C = 2048;
    int l = fb - 20480; bxi = l & 63; byi = l >> 6;
  }
  int tx = threadIdx.x & 31, ty = threadIdx.x >> 5;
  int bx = bxi * 32, by = byi * 32;
#pragma unroll
  for (int i = 0; i < 4; i++)
    tile[ty + i * 8][tx] = in[(size_t)(by + ty + i * 8) * C + bx + tx];
  __syncthreads();
#pragma unroll
  for (int i = 0; i < 4; i++)
    out[(size_t)(bx + ty + i * 8) * R + by + tx] = f2bf(tile[tx][ty + i * 8]);
}

// ---------------- GEMM m97-style (kept for out-proj) ----------------

template <int OUT_BF16>
__global__ __launch_bounds__(256) void k_gemm_bt(const u16* __restrict__ A,
                                                 const u16* __restrict__ Bt,
                                                 void* __restrict__ C, int M, int N, int K) {
  __shared__ u16 As[128 * 64];
  __shared__ u16 Bs[128 * 64];
  const int tid = threadIdx.x;
  const int lane = tid & 63;
  const int w = tid >> 6;
  const int l15 = lane & 15, l4 = lane >> 4;
  const int wr = w >> 1, wc = w & 1;
  const int bx = blockIdx.x, by = blockIdx.y;

  f32x4 acc[4][4];
#pragma unroll
  for (int a = 0; a < 4; a++)
#pragma unroll
    for (int b2 = 0; b2 < 4; b2++) acc[a][b2] = (f32x4){0.f, 0.f, 0.f, 0.f};

  const u16* Abase = A + (size_t)by * 128 * K;
  const u16* Bbase = Bt + (size_t)bx * 128 * K;

  for (int kk = 0; kk < K; kk += 64) {
    __syncthreads();
#pragma unroll
    for (int j = 0; j < 4; j++) {
      int ci = w * 256 + j * 64 + lane;
      int row = ci >> 3, c = ci & 7;
      gload16(Abase + (size_t)row * K + kk + c * 8, (char*)As + ci * 16);
      gload16(Bbase + (size_t)row * K + kk + c * 8, (char*)Bs + ci * 16);
    }
    __syncthreads();
#pragma unroll
    for (int kc = 0; kc < 2; kc++) {
      int kb = kc * 64 + l4 * 16;
      bf16x8 av[4], bv[4];
#pragma unroll
      for (int mt = 0; mt < 4; mt++)
        av[mt] = *(const bf16x8*)((const char*)As + (wr * 64 + mt * 16 + l15) * 128 + kb);
#pragma unroll
      for (int nt = 0; nt < 4; nt++)
        bv[nt] = *(const bf16x8*)((const char*)Bs + (wc * 64 + nt * 16 + l15) * 128 + kb);
#pragma unroll
      for (int mt = 0; mt < 4; mt++)
#pragma unroll
        for (int nt = 0; nt < 4; nt++) acc[mt][nt] = MFMA16(av[mt], bv[nt], acc[mt][nt]);
    }
  }
#pragma unroll
  for (int mt = 0; mt < 4; mt++) {
#pragma unroll
    for (int nt = 0; nt < 4; nt++) {
      int col = bx * 128 + wc * 64 + nt * 16 + l15;
#pragma unroll
      for (int r = 0; r < 4; r++) {
        int row = by * 128 + wr * 64 + mt * 16 + l4 * 4 + r;
        if (OUT_BF16)
          ((u16*)C)[(size_t)row * N + col] = f2bf(acc[mt][nt][r]);
        else
          ((float*)C)[(size_t)row * N + col] = acc[mt][nt][r];
      }
    }
  }
}

// ---------------- GEMM 256x256 8-phase + fused RoPE / V-transpose epilogues ----------------

__global__ __launch_bounds__(512, 1) void k_gemm256(const u16* __restrict__ A,
                                                    const u16* __restrict__ Bt,
                                                    u16* __restrict__ C, int N, int K,
                                                    const float2* __restrict__ tab,
                                                    u16* __restrict__ Vt) {
  extern __shared__ char smem[];
  const int tid = threadIdx.x;
  const int lane = tid & 63, w = tid >> 6;
  const int l15 = lane & 15, l4 = lane >> 4;
  const int wr = w >> 2, wc = w & 3;
  const int bx = blockIdx.x, by = blockIdx.y;
  const int NT = K >> 6;

  const u16* Ab = A + (size_t)(by * 256) * K;
  const u16* Bb = Bt + (size_t)(bx * 256) * K;

  int srcoff[2], dstoff[2];
#pragma unroll
  for (int rr = 0; rr < 2; rr++) {
    int ci = rr * 512 + tid;
    int lc = ci ^ (((ci >> 5) & 1) << 1);
    int kc = lc >> 9, row = (lc >> 2) & 127, g2 = lc & 3;
    srcoff[rr] = row * K + kc * 32 + g2 * 8;
    dstoff[rr] = ci * 16;
  }

  auto SH = [&](int Tg, int halfidx) {
    const u16* base = (halfidx < 2) ? (Ab + (size_t)(halfidx * 128) * K)
                                    : (Bb + (size_t)((halfidx - 2) * 128) * K);
    char* dst = smem + (Tg & 1) * 65536 + halfidx * 16384;
    int kk = Tg * 64;
#pragma unroll
    for (int rr = 0; rr < 2; rr++)
      gload16(base + srcoff[rr] + kk, dst + dstoff[rr]);
  };

  auto lda = [&](int c, int kc, int mrow4) -> bf16x8 {
    int L = kc * 8192 + (mrow4 * 16 + l15) * 64 + l4 * 16;
    int P = L ^ (((L >> 9) & 1) << 5);
    return *(const bf16x8*)(smem + c * 65536 + wr * 16384 + P);
  };
  auto ldb = [&](int c, int kc, int j) -> bf16x8 {
    int L = kc * 8192 + ((wc & 1) * 64 + j * 16 + l15) * 64 + l4 * 16;
    int P = L ^ (((L >> 9) & 1) << 5);
    return *(const bf16x8*)(smem + c * 65536 + 32768 + (wc >> 1) * 16384 + P);
  };

  f32x4 acc[8][4];
#pragma unroll
  for (int i = 0; i < 8; i++)
#pragma unroll
    for (int j = 0; j < 4; j++) acc[i][j] = (f32x4){0.f, 0.f, 0.f, 0.f};

  SH(0, 0); SH(0, 1); SH(0, 2); SH(0, 3);
  SH(1, 2); SH(1, 3);
  asm volatile("s_waitcnt vmcnt(4)" ::: "memory");
  __builtin_amdgcn_s_barrier();
  asm volatile("" ::: "memory");

  bf16x8 bv[2][4];
  for (int T = 0; T < NT; ++T) {
    const int c = T & 1;
#pragma unroll
    for (int q = 0; q < 4; q++) {
      const int kc = q & 1, mh = q >> 1;
      bf16x8 av[4];
      if (q < 2) {
#pragma unroll
        for (int j = 0; j < 4; j++) bv[kc][j] = ldb(c, kc, j);
      }
#pragma unroll
      for (int ii = 0; ii < 4; ii++) av[ii] = lda(c, kc, mh * 4 + ii);
      if (q == 0)      { if (T + 1 < NT) SH(T + 1, 0); }
      else if (q == 1) { if (T + 1 < NT) SH(T + 1, 1); }
      else if (q == 2) { if (T + 2 < NT) SH(T + 2, 2); }
      else             { if (T + 2 < NT) SH(T + 2, 3); }
      if (q == 3) {
        if (T < NT - 2)       asm volatile("s_waitcnt vmcnt(4)" ::: "memory");
        else if (T == NT - 2) asm volatile("s_waitcnt vmcnt(0)" ::: "memory");
      }
      asm volatile("" ::: "memory");
      __builtin_amdgcn_s_barrier();
      asm volatile("" ::: "memory");
      asm volatile("s_waitcnt lgkmcnt(0)" ::: "memory");
      __builtin_amdgcn_sched_barrier(0);
      __builtin_amdgcn_s_setprio(1);
#pragma unroll
      for (int ii = 0; ii < 4; ii++)
#pragma unroll
        for (int j = 0; j < 4; j++)
          acc[mh * 4 + ii][j] = MFMA16(av[ii], bv[kc][j], acc[mh * 4 + ii][j]);
      __builtin_amdgcn_s_setprio(0);
      asm volatile("" ::: "memory");
      __builtin_amdgcn_s_barrier();
      asm volatile("" ::: "memory");
    }
  }

  if (bx < 20) {
    // ---- fused RoPE epilogue (Q + K heads), conflict-free float4 exchange ----
    float4* X4 = (float4*)smem;
    const float sgn = (wc < 2) ? -1.f : 1.f;
    const int ptid = tid ^ 128;
#pragma unroll
    for (int ih = 0; ih < 2; ih++) {
      __syncthreads();
#pragma unroll
      for (int i2 = 0; i2 < 4; i2++)
#pragma unroll
        for (int j2 = 0; j2 < 4; j2++) {
          f32x4 a = acc[ih * 4 + i2][j2];
          X4[(i2 * 4 + j2) * 512 + tid] = make_float4(a[0], a[1], a[2], a[3]);
        }
      __syncthreads();
#pragma unroll
      for (int i2 = 0; i2 < 4; i2++) {
#pragma unroll
        for (int j2 = 0; j2 < 4; j2++) {
          int col = bx * 256 + wc * 64 + j2 * 16 + l15;
          int ti = (wc & 1) * 64 + j2 * 16 + l15;
          float4 part = X4[(i2 * 4 + j2) * 512 + ptid];
          float pa[4] = {part.x, part.y, part.z, part.w};
#pragma unroll
          for (int r2 = 0; r2 < 4; r2++) {
            int row = by * 256 + wr * 128 + (ih * 4 + i2) * 16 + l4 * 4 + r2;
            float mine = acc[ih * 4 + i2][j2][r2];
            float2 t = tab[(size_t)row * 128 + ti];
            C[(size_t)row * N + col] = f2bf(mine * t.x + sgn * pa[r2] * t.y);
          }
        }
      }
    }
  } else {
    // ---- fused V-transpose epilogue: write Vt[vc][token] directly ----
    u16* lt = (u16*)smem;
    const int vbase = bx * 256 - 5120;
#pragma unroll
    for (int ih = 0; ih < 2; ih++) {
      __syncthreads();
#pragma unroll
      for (int i2 = 0; i2 < 4; i2++) {
#pragma unroll
        for (int j2 = 0; j2 < 4; j2++) {
          int col = wc * 64 + j2 * 16 + l15;
          int lrow = wr * 64 + i2 * 16 + l4 * 4;
          f32x4 a = acc[ih * 4 + i2][j2];
          ushort4 pk;
          pk.x = f2bf(a[0]); pk.y = f2bf(a[1]); pk.z = f2bf(a[2]); pk.w = f2bf(a[3]);
          *(ushort4*)&lt[col * 136 + lrow] = pk;
        }
      }
      __syncthreads();
#pragma unroll
      for (int v = 0; v < 8; v++) {
        int idx2 = v * 512 + tid;
        int vc = idx2 >> 4, tv = idx2 & 15;
        bf16x8 val = *(const bf16x8*)&lt[vc * 136 + tv * 8];
        int token = by * 256 + ((tv < 8) ? (ih * 64 + tv * 8) : (128 + ih * 64 + (tv - 8) * 8));
        *(bf16x8*)&Vt[(size_t)(vbase + vc) * 4096 + token] = val;
      }
    }
  }
}

// ---------------- flash attention: split-KV (independent half-blocks) ----------------
// 1024 blocks x 256 thr (4 waves): (b,kv)=flat&7 (XCD-pinned), idx=flat>>3:
// g=idx&1 (KV half), e=idx>>1 -> qb=15-(e>>2) (heavy first), h=kv*4+(e&3).
// Half g covers tiles [g*(2qb+2), (g+1)*(2qb+2)). All blocks <=32 trips ->
// scheduler keeps ~2 live blocks/CU throughout (fixes solo-block decay).
// g=0 partial -> AO, g=1 partial -> Pd (d_out scratch); m/l -> ML. k_merge combines.

__shared__ __align__(16) u16 aK0[8192];
__shared__ __align__(16) u16 aK1[8192];
__shared__ __align__(16) u16 aV0[8192];
__shared__ __align__(16) u16 aV1[8192];

__global__ __launch_bounds__(256, 2) void k_attn(const u16* __restrict__ QKV,
                                                 const u16* __restrict__ Vt,
                                                 u16* __restrict__ AO,
                                                 u16* __restrict__ Pd,
                                                 float2* __restrict__ ML) {
  const int tid = threadIdx.x, lane = tid & 63, w = tid >> 6;
  const int r31 = lane & 31, hi = lane >> 5;

  const int flat = blockIdx.x;
  const int r = flat & 7;
  const int idx = flat >> 3;
  const int b = r >> 2, kv = r & 3;
  const int g = idx & 1;
  const int e = idx >> 1;
  const int qb = 15 - (e >> 2);      // heavy first
  const int h = kv * 4 + (e & 3);

  bf16x8 qreg[16];
  {
    const u16* qp = QKV + (size_t)(b * 2048 + qb * 128 + w * 32 + r31) * QKVS + h * 256 + hi * 8;
#pragma unroll
    for (int kc = 0; kc < 16; kc++) qreg[kc] = *(const bf16x8*)(qp + kc * 16);
  }

  f32x16 o[8];
#pragma unroll
  for (int df = 0; df < 8; df++)
#pragma unroll
    for (int jj = 0; jj < 16; jj++) o[df][jj] = 0.f;
  float mrow = -3e38f, lrow = 0.f;

  const int hh = 2 * qb + 2;         // trips in this half (even)
  const int t0 = g * hh;
  const int tlim = 4 * qb + w;
  const int qloc = qb * 128 + w * 32 + r31;
  const u16* Kbase = QKV + (size_t)(b * 2048) * QKVS + 4096 + kv * 256;
  const u16* Vbase = Vt + (size_t)(kv * 256) * 4096 + b * 2048;

  int kfix[4], vfix[4];
#pragma unroll
  for (int jj = 0; jj < 4; jj++) {
    int ci = jj * 256 + tid;
    int krow = ci >> 5, kc = ci & 31;
    int kcg = (kc & 24) | ((kc ^ krow) & 7);
    kfix[jj] = krow * QKVS + kcg * 8;
    int vrow = ci >> 2, vc = ci & 3;
    int vg = (vc - (vrow >> 1)) & 3;
    vfix[jj] = vrow * 4096 + vg * 8;
  }
  int koff = t0 * 32 * QKVS, voff = t0 * 32;

  auto STAGE = [&](u16* Kd, u16* Vd) {
#pragma unroll
    for (int jj = 0; jj < 4; jj++)
      gload16(Kbase + kfix[jj] + koff, (char*)Kd + (jj * 256 + tid) * 16);
#pragma unroll
    for (int jj = 0; jj < 4; jj++)
      gload16(Vbase + vfix[jj] + voff, (char*)Vd + (jj * 256 + tid) * 16);
    koff += 32 * QKVS;
    voff += 32;
  };

  auto COMPUTE = [&](int t, const u16* Kc, const u16* Vc) {
    f32x16 s;
#pragma unroll
    for (int jj = 0; jj < 16; jj++) s[jj] = 0.f;
#pragma unroll
    for (int kc = 0; kc < 16; kc++) {
      int ch = kc * 2 + hi;
      int cs = (ch & 24) | ((ch ^ r31) & 7);
      bf16x8 kf = *(const bf16x8*)((const char*)Kc + r31 * 512 + cs * 16);
      s = MFMA32(kf, qreg[kc], s);
    }

    const float C = 0.0625f * LOG2E;
    float z[16];
#pragma unroll
    for (int jj = 0; jj < 16; jj++) z[jj] = s[jj] * C;
    if (t == tlim) {
#pragma unroll
      for (int jj = 0; jj < 16; jj++) {
        int kvg = t * 32 + (jj & 3) + 8 * (jj >> 2) + 4 * hi;
        if (kvg > qloc) z[jj] = -1e30f;
      }
    }

    float m0 = z[0];
#pragma unroll
    for (int jj = 1; jj < 16; jj++) m0 = fmaxf(m0, z[jj]);
    m0 = fmaxf(m0, __shfl_xor(m0, 32));
    if (__any(m0 > mrow + 11.54f)) {
      float mn = fmaxf(mrow, m0);
      float alpha = exp2f(mrow - mn);
      mrow = mn;
      lrow *= alpha;
#pragma unroll
      for (int jj = 0; jj < 16; jj++) {
        float a = __shfl(alpha, (jj & 3) + 8 * (jj >> 2) + 4 * hi);
#pragma unroll
        for (int df = 0; df < 8; df++) o[df][jj] *= a;
      }
    }
    float sum = 0.f;
#pragma unroll
    for (int jj = 0; jj < 16; jj++) {
      z[jj] = exp2f(z[jj] - mrow);
      sum += z[jj];
    }
    sum += __shfl_xor(sum, 32);
    lrow += sum;

    unsigned a0 = cvtpk(z[0], z[1]), a2 = cvtpk(z[4], z[5]);
    swap32(a0, a2);
    unsigned a1 = cvtpk(z[2], z[3]), a3 = cvtpk(z[6], z[7]);
    swap32(a1, a3);
    unsigned b0 = cvtpk(z[8], z[9]), b2 = cvtpk(z[12], z[13]);
    swap32(b0, b2);
    unsigned b1 = cvtpk(z[10], z[11]), b3 = cvtpk(z[14], z[15]);
    swap32(b1, b3);
    union UU { unsigned u[4]; bf16x8 v; };
    UU ua; ua.u[0] = a0; ua.u[1] = a1; ua.u[2] = a2; ua.u[3] = a3;
    UU ub; ub.u[0] = b0; ub.u[1] = b1; ub.u[2] = b2; ub.u[3] = b3;
    bf16x8 pa0 = ua.v, pa1 = ub.v;

#pragma unroll
    for (int df = 0; df < 8; df++) {
      int vr = df * 32 + r31;
      int c0 = (hi + (vr >> 1)) & 3;
      int c1 = (2 + hi + (vr >> 1)) & 3;
      bf16x8 v0 = *(const bf16x8*)((const char*)Vc + vr * 64 + c0 * 16);
      bf16x8 v1 = *(const bf16x8*)((const char*)Vc + vr * 64 + c1 * 16);
      o[df] = MFMA32(pa0, v0, o[df]);
      o[df] = MFMA32(pa1, v1, o[df]);
    }
  };

  STAGE(aK0, aV0);
  __syncthreads();

  for (int tt = 0; tt < hh; tt += 2) {
    int t = t0 + tt;
    STAGE(aK1, aV1);  // t+1 (tt+1 < hh: hh even)
    if (t <= tlim) COMPUTE(t, aK0, aV0);
    __syncthreads();
    if (tt + 2 < hh) STAGE(aK0, aV0);
    if (t + 1 <= tlim) COMPUTE(t + 1, aK1, aV1);
    __syncthreads();
  }

  // ---- partial epilogue: own-l-normalized o (bf16), plus (m, l) ----
  float rl = (lrow > 0.f) ? 1.f / lrow : 0.f;
  u16* dst = g ? Pd : AO;
  size_t rowbase = (size_t)(b * 2048 + qb * 128 + w * 32);
#pragma unroll
  for (int jj = 0; jj < 16; jj++) {
    float rr2 = __shfl(rl, (jj & 3) + 8 * (jj >> 2) + 4 * hi);
    int qr = (jj & 3) + 8 * (jj >> 2) + 4 * hi;
#pragma unroll
    for (int df = 0; df < 8; df++)
      dst[(rowbase + qr) * 4096 + h * 256 + df * 32 + r31] = f2bf(o[df][jj] * rr2);
  }
  if (hi == 0) {  // one lane set per q-row
    int token = b * 2048 + qloc;
    ML[g * 65536 + token * 16 + h] = make_float2(mrow, lrow);
  }
}

// ---------------- merge of the two KV-half partials ----------------
// out = (o0 * l0*exp2(m0-mm) + o1 * l1*exp2(m1-mm)) / (w0 + w1). l0>0 always
// (g=0 computes >=1 tile per row); empty g=1 halves have l1=0, m1=-3e38 -> w1=0.
__global__ __launch_bounds__(256) void k_merge(u16* __restrict__ AO,
                                               const u16* __restrict__ Pd,
                                               const float2* __restrict__ ML) {
  int idx = blockIdx.x * 256 + threadIdx.x;  // 2,097,152 total
  int rh = idx >> 5, dblk = idx & 31;
  float2 ml0 = ML[rh], ml1 = ML[65536 + rh];
  float mm = fmaxf(ml0.x, ml1.x);
  float w0 = ml0.y * exp2f(ml0.x - mm);
  float w1 = ml1.y * exp2f(ml1.x - mm);
  float rs = 1.f / (w0 + w1);
  size_t off = (size_t)rh * 256 + dblk * 8;  // rh*256 == token*4096 + h*256
  union BU { bf16x8 v; u16 a[8]; };
  BU a, bb, o;
  a.v = *(const bf16x8*)(AO + off);
  bb.v = *(const bf16x8*)(Pd + off);
#pragma unroll
  for (int e = 0; e < 8; e++)
    o.a[e] = f2bf((bf2f(a.a[e]) * w0 + bf2f(bb.a[e]) * w1) * rs);
  *(bf16x8*)(AO + off) = o.v;
}

// ---------------- host ----------------

// ws layout (bytes), high-water 121.6 MB (unchanged from r19):
// AO @0 (32MB) aliases Xb (dead) + Wqkvt head (dead post-gemm).
// Wqkvt @16.7M (25.2MB, dead after gemm256). ML @33.55M (1MB, in the free gap).
// Wot @41.9M (16.8MB, persists). QKV @58.7M (48MB). TAB @109.1M (4MB). VT @113.2M (8MB).
// g=1 partial lives in d_out (32MB bf16 scratch; out-proj overwrites it after merge).
#define OFF_AO    0u
#define OFF_XB    0u
#define OFF_WQKVT 16777216u
#define OFF_ML    33554432u
#define OFF_WOT   41943040u
#define OFF_QKV   58720256u
#define OFF_TAB   109051904u
#define OFF_VT    113246208u

extern "C" void kernel_launch(void* const* d_in, const int* in_sizes, int n_in,
                              void* d_out, int out_size, void* d_ws, size_t ws_size,
                              hipStream_t stream) {
  const float* hs = (const float*)d_in[0];
  const int* pos = (const int*)d_in[1];
  const float* wq = (const float*)d_in[2];
  const float* wk = (const float*)d_in[3];
  const float* wv = (const float*)d_in[4];
  const float* wo = (const float*)d_in[5];
  float* out = (float*)d_out;
  char* ws = (char*)d_ws;

  u16* Xb    = (u16*)(ws + OFF_XB);
  u16* Wqkvt = (u16*)(ws + OFF_WQKVT);
  float2* ML = (float2*)(ws + OFF_ML);
  u16* Wot   = (u16*)(ws + OFF_WOT);
  u16* QKV   = (u16*)(ws + OFF_QKV);
  float2* Tab = (float2*)(ws + OFF_TAB);
  u16* Vt    = (u16*)(ws + OFF_VT);
  u16* AO    = (u16*)(ws + OFF_AO);
  u16* Pd    = (u16*)d_out;  // 32MB scratch for g=1 partial; overwritten by out-proj

  // unified prep: convert + all weight transposes + rope table (one launch)
  k_prep<<<30720, 256, 0, stream>>>(hs, pos, wq, wk, wv, wo, Xb, Wqkvt, Wot, Tab);

  // fused QKV projection + RoPE epilogue (Q/K) + V-transpose epilogue (V)
  (void)hipFuncSetAttribute((const void*)k_gemm256,
                            hipFuncAttributeMaxDynamicSharedMemorySize, 131072);
  k_gemm256<<<dim3(24, 16), 512, 131072, stream>>>(Xb, Wqkvt, QKV, 6144, 2048, Tab, Vt);

  // flash attention: split-KV halves (1024 blocks), partials to AO / Pd + ML
  k_attn<<<dim3(1024), 256, 0, stream>>>(QKV, Vt, AO, Pd, ML);

  // merge the two halves into AO
  k_merge<<<8192, 256, 0, stream>>>(AO, Pd, ML);

  // output projection (fp32 out), m97 structure
  k_gemm_bt<0><<<dim3(16, 32), 256, 0, stream>>>(AO, Wot, out, 4096, 2048, 4096);
}